// Round 1
// baseline (10498.782 us; speedup 1.0000x reference)
//
#include <hip/hip_runtime.h>
#include <hip/hip_bf16.h>
#include <math.h>

// Problem constants
#define Bq 2
#define Tq 2048
#define Cq 1024
#define Hq 16
#define Dq 64
#define Eq 8
#define HDq 1536
#define NTOK (Bq*Tq)        // 4096 tokens

__device__ __forceinline__ float silu_f(float a) {
    return a / (1.0f + __expf(-a));
}

// ---------------------------------------------------------------------------
// RMSNorm: one block per row of C=1024, 256 threads, float4 per thread.
// ---------------------------------------------------------------------------
__global__ __launch_bounds__(256) void rmsnorm_k(const float* __restrict__ x,
                                                 const float* __restrict__ w,
                                                 float* __restrict__ out) {
    int row = blockIdx.x;
    int tid = threadIdx.x;
    const float* xr = x + (size_t)row * Cq;
    float4 v = *(const float4*)(xr + tid * 4);
    float ss = v.x*v.x + v.y*v.y + v.z*v.z + v.w*v.w;
    #pragma unroll
    for (int off = 32; off; off >>= 1) ss += __shfl_xor(ss, off);
    __shared__ float red[4];
    if ((tid & 63) == 0) red[tid >> 6] = ss;
    __syncthreads();
    float tot = red[0] + red[1] + red[2] + red[3];
    float scale = rsqrtf(tot * (1.0f / (float)Cq) + 1e-6f);
    float4 wv = *(const float4*)(w + tid * 4);
    float4 o;
    o.x = v.x * wv.x * scale;
    o.y = v.y * wv.y * scale;
    o.z = v.z * wv.z * scale;
    o.w = v.w * wv.w * scale;
    *(float4*)(out + (size_t)row * Cq + tid * 4) = o;
}

// ---------------------------------------------------------------------------
// Tiled fp32 GEMM: C[M,N] = A[M,K] @ W[N,K]^T  (both row-major, B-transposed
// weight layout, which is exactly how all weights here are stored).
// 64x64 tile, BK=16, 256 threads, 4x4 microtile/thread.
// LDS stored k-major ([k][row], stride 68 for alignment+bank spread) so the
// inner loop is 2x ds_read_b128 + 16 v_fma per kk.
// mode 0: C = acc
// mode 1: C = aux + acc                 (residual add; aux is x)
// mode 2: C += aux[m*8+e] * acc         (MoE gated accumulate into d_out)
// mode 3: C = silu(acc) * C             (SwiGLU fuse; C holds h@w3^T)
// ---------------------------------------------------------------------------
__global__ __launch_bounds__(256) void gemm_bt(const float* __restrict__ A,
                                               const float* __restrict__ W,
                                               float* __restrict__ C,
                                               int M, int N, int K,
                                               const float* __restrict__ aux,
                                               int mode, int e) {
    __shared__ float As[16][68];
    __shared__ float Ws[16][68];
    int tid = threadIdx.x;
    int bx = blockIdx.x;  // N tile
    int by = blockIdx.y;  // M tile

    int lrow = tid >> 2;        // 0..63
    int lk4  = (tid & 3) * 4;   // 0,4,8,12

    const float* Ab = A + (size_t)(by * 64) * K;
    const float* Wb = W + (size_t)(bx * 64) * K;

    float acc[4][4] = {};

    for (int k0 = 0; k0 < K; k0 += 16) {
        float4 av = *(const float4*)(Ab + (size_t)lrow * K + k0 + lk4);
        float4 wv = *(const float4*)(Wb + (size_t)lrow * K + k0 + lk4);
        As[lk4 + 0][lrow] = av.x;
        As[lk4 + 1][lrow] = av.y;
        As[lk4 + 2][lrow] = av.z;
        As[lk4 + 3][lrow] = av.w;
        Ws[lk4 + 0][lrow] = wv.x;
        Ws[lk4 + 1][lrow] = wv.y;
        Ws[lk4 + 2][lrow] = wv.z;
        Ws[lk4 + 3][lrow] = wv.w;
        __syncthreads();
        int ty4 = (tid >> 4) * 4;
        int tx4 = (tid & 15) * 4;
        #pragma unroll
        for (int kk = 0; kk < 16; kk++) {
            float4 a = *(const float4*)&As[kk][ty4];
            float4 b = *(const float4*)&Ws[kk][tx4];
            float ar[4] = {a.x, a.y, a.z, a.w};
            float br[4] = {b.x, b.y, b.z, b.w};
            #pragma unroll
            for (int i = 0; i < 4; i++)
                #pragma unroll
                for (int j = 0; j < 4; j++)
                    acc[i][j] = fmaf(ar[i], br[j], acc[i][j]);
        }
        __syncthreads();
    }

    int m0 = by * 64 + (tid >> 4) * 4;
    int n0 = bx * 64 + (tid & 15) * 4;
    #pragma unroll
    for (int i = 0; i < 4; i++) {
        size_t off = (size_t)(m0 + i) * N + n0;
        if (mode == 0) {
            float4 o = make_float4(acc[i][0], acc[i][1], acc[i][2], acc[i][3]);
            *(float4*)(C + off) = o;
        } else if (mode == 1) {
            float4 r = *(const float4*)(aux + off);
            float4 o = make_float4(acc[i][0] + r.x, acc[i][1] + r.y,
                                   acc[i][2] + r.z, acc[i][3] + r.w);
            *(float4*)(C + off) = o;
        } else if (mode == 2) {
            float gw = aux[(size_t)(m0 + i) * Eq + e];
            float4 c = *(float4*)(C + off);
            c.x += gw * acc[i][0];
            c.y += gw * acc[i][1];
            c.z += gw * acc[i][2];
            c.w += gw * acc[i][3];
            *(float4*)(C + off) = c;
        } else {
            float4 c = *(float4*)(C + off);
            c.x *= silu_f(acc[i][0]);
            c.y *= silu_f(acc[i][1]);
            c.z *= silu_f(acc[i][2]);
            c.w *= silu_f(acc[i][3]);
            *(float4*)(C + off) = c;
        }
    }
}

// ---------------------------------------------------------------------------
// RoPE, in place on q and k. Each thread owns one (d, d+32) pair -> no race.
// Layout of q/k: row = b*T+t, col = h*64+d.
// ---------------------------------------------------------------------------
__global__ __launch_bounds__(256) void rope_k(float* __restrict__ q,
                                              float* __restrict__ k,
                                              const float* __restrict__ cosb,
                                              const float* __restrict__ sinb) {
    int idx = blockIdx.x * 256 + threadIdx.x;   // 0 .. 2*4096*512-1
    int p = idx & 511;                          // pair index within row
    int row = (idx >> 9) & (NTOK - 1);
    float* buf = (idx >> 21) ? k : q;
    int h = p >> 5, d = p & 31;
    int t = row & (Tq - 1);                     // row = b*T + t
    size_t base = (size_t)row * Cq + h * Dq + d;
    float a = buf[base];
    float b = buf[base + 32];
    float c0 = cosb[t * Dq + d],      s0 = sinb[t * Dq + d];
    float c1 = cosb[t * Dq + d + 32], s1 = sinb[t * Dq + d + 32];
    buf[base]      = a * c0 - b * s0;
    buf[base + 32] = b * c1 + a * s1;
}

// ---------------------------------------------------------------------------
// Causal attention, online softmax. One wave per query row; lane = d (0..63).
// K/V for one (b,h) is 512KB each -> L2-resident across the 2048 q-rows.
// ---------------------------------------------------------------------------
__global__ __launch_bounds__(256) void attn_k(const float* __restrict__ q,
                                              const float* __restrict__ k,
                                              const float* __restrict__ v,
                                              float* __restrict__ y) {
    int w = blockIdx.x * 4 + (threadIdx.x >> 6);
    int lane = threadIdx.x & 63;
    int qi = w & (Tq - 1);
    int bh = w >> 11;            // 0..31
    int b = bh >> 4, h = bh & 15;
    size_t qoff  = ((size_t)(b * Tq + qi)) * Cq + h * Dq + lane;
    size_t kbase = ((size_t)(b * Tq)) * Cq + h * Dq + lane;
    float qv = q[qoff] * 0.125f;  // 1/sqrt(64)
    float m = -1e30f, l = 0.0f, acc = 0.0f;
    for (int ki = 0; ki <= qi; ki++) {
        float kv = k[kbase + (size_t)ki * Cq];
        float s = qv * kv;
        #pragma unroll
        for (int off = 32; off; off >>= 1) s += __shfl_xor(s, off);
        float mn = fmaxf(m, s);
        float alpha = __expf(m - mn);
        float p = __expf(s - mn);
        l = l * alpha + p;
        float vv = v[kbase + (size_t)ki * Cq];
        acc = acc * alpha + p * vv;
        m = mn;
    }
    y[qoff] = acc / l;
}

// ---------------------------------------------------------------------------
// Router: one wave per token. Computes 8 logits, top-2, softmax over the 2,
// writes a dense gate vector of 8 floats per token (zeros elsewhere).
// ---------------------------------------------------------------------------
__global__ __launch_bounds__(64) void router_k(const float* __restrict__ hn,
                                               const float* __restrict__ rw,
                                               float* __restrict__ gate) {
    int tkn = blockIdx.x;
    int lane = threadIdx.x;
    float acc[Eq] = {};
    for (int it = 0; it < Cq / 64; it++) {
        float hv = hn[(size_t)tkn * Cq + it * 64 + lane];
        #pragma unroll
        for (int e = 0; e < Eq; e++)
            acc[e] = fmaf(hv, rw[e * Cq + it * 64 + lane], acc[e]);
    }
    #pragma unroll
    for (int e = 0; e < Eq; e++) {
        #pragma unroll
        for (int off = 32; off; off >>= 1) acc[e] += __shfl_xor(acc[e], off);
    }
    int i0 = 0;
    #pragma unroll
    for (int e = 1; e < Eq; e++) if (acc[e] > acc[i0]) i0 = e;
    int i1 = (i0 == 0) ? 1 : 0;
    #pragma unroll
    for (int e = 0; e < Eq; e++)
        if (e != i0 && acc[e] > acc[i1]) i1 = e;
    float p1 = __expf(acc[i1] - acc[i0]);
    float g0 = 1.0f / (1.0f + p1);
    float g1 = p1 / (1.0f + p1);
    if (lane < Eq)
        gate[(size_t)tkn * Eq + lane] = (lane == i0) ? g0 : ((lane == i1) ? g1 : 0.0f);
}

// ---------------------------------------------------------------------------
// Launch
// ---------------------------------------------------------------------------
extern "C" void kernel_launch(void* const* d_in, const int* in_sizes, int n_in,
                              void* d_out, int out_size, void* d_ws, size_t ws_size,
                              hipStream_t stream) {
    (void)in_sizes; (void)n_in; (void)out_size; (void)ws_size;

    const float* x       = (const float*)d_in[0];
    const float* ropec   = (const float*)d_in[1];
    const float* ropes   = (const float*)d_in[2];
    const float* anw     = (const float*)d_in[3];
    const float* q_w     = (const float*)d_in[4];
    const float* k_w     = (const float*)d_in[5];
    const float* v_w     = (const float*)d_in[6];
    const float* o_w     = (const float*)d_in[7];
    const float* fnw     = (const float*)d_in[8];
    const float* rtw     = (const float*)d_in[9];
    const float* w1      = (const float*)d_in[10];
    const float* w2      = (const float*)d_in[11];
    const float* w3      = (const float*)d_in[12];
    float* out = (float*)d_out;

    // workspace layout (floats). 4M = one 4096x1024 fp32 matrix.
    const size_t M4 = (size_t)NTOK * Cq;    // 4194304
    float* ws  = (float*)d_ws;
    float* h   = ws;                        // [0,4M)   h, later y
    float* qb  = ws + M4;                   // [4M,8M)  q, later hn
    float* kb  = ws + 2 * M4;               // [8M,12M) k, later gate
    float* vb  = ws + 3 * M4;               // [12M,..) v, later g (4096x1536)
    float* yb   = h;
    float* hn   = qb;
    float* gate = kb;
    float* g    = vb;                       // 4096*1536 floats = [12M,18M)

    const int M = NTOK;

    // 1. attn rmsnorm
    hipLaunchKernelGGL(rmsnorm_k, dim3(M), dim3(256), 0, stream, x, anw, h);

    // 2-4. Q,K,V projections
    hipLaunchKernelGGL(gemm_bt, dim3(Cq / 64, M / 64), dim3(256), 0, stream,
                       h, q_w, qb, M, Cq, Cq, (const float*)nullptr, 0, 0);
    hipLaunchKernelGGL(gemm_bt, dim3(Cq / 64, M / 64), dim3(256), 0, stream,
                       h, k_w, kb, M, Cq, Cq, (const float*)nullptr, 0, 0);
    hipLaunchKernelGGL(gemm_bt, dim3(Cq / 64, M / 64), dim3(256), 0, stream,
                       h, v_w, vb, M, Cq, Cq, (const float*)nullptr, 0, 0);

    // 5. RoPE on q,k in-place
    hipLaunchKernelGGL(rope_k, dim3((2 * NTOK * 512) / 256), dim3(256), 0, stream,
                       qb, kb, ropec, ropes);

    // 6. attention -> y (overwrites h)
    hipLaunchKernelGGL(attn_k, dim3((Bq * Hq * Tq) / 4), dim3(256), 0, stream,
                       qb, kb, vb, yb);

    // 7. O projection + residual -> d_out = x2
    hipLaunchKernelGGL(gemm_bt, dim3(Cq / 64, M / 64), dim3(256), 0, stream,
                       yb, o_w, out, M, Cq, Cq, x, 1, 0);

    // 8. ffn rmsnorm -> hn (overwrites q)
    hipLaunchKernelGGL(rmsnorm_k, dim3(M), dim3(256), 0, stream, out, fnw, hn);

    // 9. router -> gate (overwrites k)
    hipLaunchKernelGGL(router_k, dim3(M), dim3(64), 0, stream, hn, rtw, gate);

    // 10. MoE, dense over all experts (gate zeros mask unassigned tokens)
    for (int e = 0; e < Eq; e++) {
        const float* w1e = w1 + (size_t)e * HDq * Cq;
        const float* w2e = w2 + (size_t)e * Cq * HDq;
        const float* w3e = w3 + (size_t)e * HDq * Cq;
        // g = hn @ w3^T
        hipLaunchKernelGGL(gemm_bt, dim3(HDq / 64, M / 64), dim3(256), 0, stream,
                           hn, w3e, g, M, HDq, Cq, (const float*)nullptr, 0, 0);
        // g = silu(hn @ w1^T) * g
        hipLaunchKernelGGL(gemm_bt, dim3(HDq / 64, M / 64), dim3(256), 0, stream,
                           hn, w1e, g, M, HDq, Cq, (const float*)nullptr, 3, 0);
        // out += gate[:,e] * (g @ w2^T)
        hipLaunchKernelGGL(gemm_bt, dim3(Cq / 64, M / 64), dim3(256), 0, stream,
                           g, w2e, out, M, Cq, HDq, gate, 2, e);
    }
}

// Round 2
// 2677.441 us; speedup vs baseline: 3.9212x; 3.9212x over previous
//
#include <hip/hip_runtime.h>
#include <hip/hip_bf16.h>
#include <math.h>

// Problem constants
#define Bq 2
#define Tq 2048
#define Cq 1024
#define Hq 16
#define Dq 64
#define Eq 8
#define HDq 1536
#define NTOK (Bq*Tq)        // 4096 tokens

typedef unsigned short ushort_t;
typedef __bf16 bf16x8 __attribute__((ext_vector_type(8)));
typedef float f32x4v __attribute__((ext_vector_type(4)));

__device__ __forceinline__ float silu_f(float a) {
    return a / (1.0f + __expf(-a));
}

// fp32 -> bf16 round-to-nearest-even
__device__ __forceinline__ ushort_t f2bf(float f) {
    union { float f; unsigned u; } a; a.f = f;
    unsigned r = a.u + 0x7fffu + ((a.u >> 16) & 1u);
    return (ushort_t)(r >> 16);
}
__device__ __forceinline__ float bf2f(ushort_t u) {
    union { unsigned u; float f; } a; a.u = ((unsigned)u) << 16;
    return a.f;
}

// async global->LDS, 16B per lane (dst must be wave-uniform base + lane*16)
__device__ __forceinline__ void stage16(const void* g, void* l) {
#if __has_builtin(__builtin_amdgcn_global_load_lds)
    __builtin_amdgcn_global_load_lds(
        (const __attribute__((address_space(1))) unsigned int*)g,
        (__attribute__((address_space(3))) unsigned int*)l, 16, 0, 0);
#else
    *(uint4*)l = *(const uint4*)g;
#endif
}

// ---------------------------------------------------------------------------
// RMSNorm (fp32 out): one block per row of C=1024.
// ---------------------------------------------------------------------------
__global__ __launch_bounds__(256) void rmsnorm_k(const float* __restrict__ x,
                                                 const float* __restrict__ w,
                                                 float* __restrict__ out) {
    int row = blockIdx.x;
    int tid = threadIdx.x;
    const float* xr = x + (size_t)row * Cq;
    float4 v = *(const float4*)(xr + tid * 4);
    float ss = v.x*v.x + v.y*v.y + v.z*v.z + v.w*v.w;
    #pragma unroll
    for (int off = 32; off; off >>= 1) ss += __shfl_xor(ss, off);
    __shared__ float red[4];
    if ((tid & 63) == 0) red[tid >> 6] = ss;
    __syncthreads();
    float tot = red[0] + red[1] + red[2] + red[3];
    float scale = rsqrtf(tot * (1.0f / (float)Cq) + 1e-6f);
    float4 wv = *(const float4*)(w + tid * 4);
    float4 o;
    o.x = v.x * wv.x * scale;
    o.y = v.y * wv.y * scale;
    o.z = v.z * wv.z * scale;
    o.w = v.w * wv.w * scale;
    *(float4*)(out + (size_t)row * Cq + tid * 4) = o;
}

// ---------------------------------------------------------------------------
// fp32 tiled GEMM (QKV / O-proj only): C[M,N] = A[M,K] @ W[N,K]^T
// mode 0: C = acc ; mode 1: C = aux + acc (residual)
// Kept fp32 on purpose: this path feeds the MoE router's top-k; bf16 here
// risks expert-selection flips (logit gaps ~0.2 vs bf16 noise ~1e-4 * 4096).
// ---------------------------------------------------------------------------
__global__ __launch_bounds__(256) void gemm_bt(const float* __restrict__ A,
                                               const float* __restrict__ W,
                                               float* __restrict__ C,
                                               int M, int N, int K,
                                               const float* __restrict__ aux,
                                               int mode) {
    __shared__ float As[16][68];
    __shared__ float Ws[16][68];
    int tid = threadIdx.x;
    int bx = blockIdx.x;  // N tile
    int by = blockIdx.y;  // M tile

    int lrow = tid >> 2;        // 0..63
    int lk4  = (tid & 3) * 4;   // 0,4,8,12

    const float* Ab = A + (size_t)(by * 64) * K;
    const float* Wb = W + (size_t)(bx * 64) * K;

    float acc[4][4] = {};

    for (int k0 = 0; k0 < K; k0 += 16) {
        float4 av = *(const float4*)(Ab + (size_t)lrow * K + k0 + lk4);
        float4 wv = *(const float4*)(Wb + (size_t)lrow * K + k0 + lk4);
        As[lk4 + 0][lrow] = av.x;
        As[lk4 + 1][lrow] = av.y;
        As[lk4 + 2][lrow] = av.z;
        As[lk4 + 3][lrow] = av.w;
        Ws[lk4 + 0][lrow] = wv.x;
        Ws[lk4 + 1][lrow] = wv.y;
        Ws[lk4 + 2][lrow] = wv.z;
        Ws[lk4 + 3][lrow] = wv.w;
        __syncthreads();
        int ty4 = (tid >> 4) * 4;
        int tx4 = (tid & 15) * 4;
        #pragma unroll
        for (int kk = 0; kk < 16; kk++) {
            float4 a = *(const float4*)&As[kk][ty4];
            float4 b = *(const float4*)&Ws[kk][tx4];
            float ar[4] = {a.x, a.y, a.z, a.w};
            float br[4] = {b.x, b.y, b.z, b.w};
            #pragma unroll
            for (int i = 0; i < 4; i++)
                #pragma unroll
                for (int j = 0; j < 4; j++)
                    acc[i][j] = fmaf(ar[i], br[j], acc[i][j]);
        }
        __syncthreads();
    }

    int m0 = by * 64 + (tid >> 4) * 4;
    int n0 = bx * 64 + (tid & 15) * 4;
    #pragma unroll
    for (int i = 0; i < 4; i++) {
        size_t off = (size_t)(m0 + i) * N + n0;
        if (mode == 0) {
            *(float4*)(C + off) = make_float4(acc[i][0], acc[i][1], acc[i][2], acc[i][3]);
        } else {
            float4 r = *(const float4*)(aux + off);
            *(float4*)(C + off) = make_float4(acc[i][0] + r.x, acc[i][1] + r.y,
                                              acc[i][2] + r.z, acc[i][3] + r.w);
        }
    }
}

// ---------------------------------------------------------------------------
// RoPE, in place on q and k (fp32).
// ---------------------------------------------------------------------------
__global__ __launch_bounds__(256) void rope_k(float* __restrict__ q,
                                              float* __restrict__ k,
                                              const float* __restrict__ cosb,
                                              const float* __restrict__ sinb) {
    int idx = blockIdx.x * 256 + threadIdx.x;
    int p = idx & 511;
    int row = (idx >> 9) & (NTOK - 1);
    float* buf = (idx >> 21) ? k : q;
    int h = p >> 5, d = p & 31;
    int t = row & (Tq - 1);
    size_t base = (size_t)row * Cq + h * Dq + d;
    float a = buf[base];
    float b = buf[base + 32];
    float c0 = cosb[t * Dq + d],      s0 = sinb[t * Dq + d];
    float c1 = cosb[t * Dq + d + 32], s1 = sinb[t * Dq + d + 32];
    buf[base]      = a * c0 - b * s0;
    buf[base + 32] = b * c1 + a * s1;
}

// ---------------------------------------------------------------------------
// Flash attention, fp32 VALU. 64x64 tiles, 256 threads, 4x4 microtile.
// Grid: (T/64 q-tiles, B*H). LDS: Q,K,V tiles (stride 68 to break bank
// strides while keeping float4 alignment). P overwrites the K tile after the
// S phase (saves 17 KB -> 3 blocks/CU instead of 2).
// ---------------------------------------------------------------------------
__global__ __launch_bounds__(256, 3) void attn_flash(const float* __restrict__ q,
                                                     const float* __restrict__ k,
                                                     const float* __restrict__ v,
                                                     float* __restrict__ y) {
    __shared__ float Qs[64][68];
    __shared__ float Ks[64][68];
    __shared__ float Vs[64][68];
    float (*Ps)[68] = Ks;   // alias: P matrix reuses K tile storage

    int qt = blockIdx.x;          // q-tile 0..31
    int bh = blockIdx.y;          // 0..31
    int b = bh >> 4, h = bh & 15;
    int tid = threadIdx.x;
    int tq = tid >> 4;            // 0..15: rows tq*4..+4
    int tk = tid & 15;            // 0..15: cols tk*4..+4
    int sr = tid >> 2;            // staging row 0..63
    int sc = (tid & 3) * 16;      // staging col
    size_t qbase  = ((size_t)b * Tq + (size_t)qt * 64) * Cq + (size_t)h * Dq;
    size_t kvbase = ((size_t)b * Tq) * Cq + (size_t)h * Dq;

    // stage Q (pre-scaled by 1/sqrt(D))
    {
        const float* src = q + qbase + (size_t)sr * Cq + sc;
        #pragma unroll
        for (int i = 0; i < 16; i += 4) {
            float4 t4 = *(const float4*)(src + i);
            Qs[sr][sc + i]     = t4.x * 0.125f;
            Qs[sr][sc + i + 1] = t4.y * 0.125f;
            Qs[sr][sc + i + 2] = t4.z * 0.125f;
            Qs[sr][sc + i + 3] = t4.w * 0.125f;
        }
    }

    float m_i[4], l_i[4], o_acc[4][4];
    #pragma unroll
    for (int i = 0; i < 4; i++) {
        m_i[i] = -1e30f; l_i[i] = 0.0f;
        #pragma unroll
        for (int j = 0; j < 4; j++) o_acc[i][j] = 0.0f;
    }

    for (int kt = 0; kt <= qt; kt++) {
        __syncthreads();   // prev PV done reading Vs/Ps; Q staged (iter 0)
        {
            const float* ksrc = k + kvbase + (size_t)(kt * 64 + sr) * Cq + sc;
            const float* vsrc = v + kvbase + (size_t)(kt * 64 + sr) * Cq + sc;
            #pragma unroll
            for (int i = 0; i < 16; i += 4) {
                float4 k4 = *(const float4*)(ksrc + i);
                float4 v4 = *(const float4*)(vsrc + i);
                Ks[sr][sc+i] = k4.x; Ks[sr][sc+i+1] = k4.y;
                Ks[sr][sc+i+2] = k4.z; Ks[sr][sc+i+3] = k4.w;
                Vs[sr][sc+i] = v4.x; Vs[sr][sc+i+1] = v4.y;
                Vs[sr][sc+i+2] = v4.z; Vs[sr][sc+i+3] = v4.w;
            }
        }
        __syncthreads();

        // S = Q K^T, 4x4 per thread
        float s[4][4] = {};
        #pragma unroll
        for (int d = 0; d < 64; d += 4) {
            float4 qv[4], kv[4];
            #pragma unroll
            for (int i = 0; i < 4; i++) qv[i] = *(const float4*)&Qs[tq*4+i][d];
            #pragma unroll
            for (int j = 0; j < 4; j++) kv[j] = *(const float4*)&Ks[tk*4+j][d];
            #pragma unroll
            for (int i = 0; i < 4; i++)
                #pragma unroll
                for (int j = 0; j < 4; j++) {
                    s[i][j] = fmaf(qv[i].x, kv[j].x, s[i][j]);
                    s[i][j] = fmaf(qv[i].y, kv[j].y, s[i][j]);
                    s[i][j] = fmaf(qv[i].z, kv[j].z, s[i][j]);
                    s[i][j] = fmaf(qv[i].w, kv[j].w, s[i][j]);
                }
        }
        if (kt == qt) {   // causal mask, diagonal tile only
            #pragma unroll
            for (int i = 0; i < 4; i++)
                #pragma unroll
                for (int j = 0; j < 4; j++)
                    if (tk*4 + j > tq*4 + i) s[i][j] = -1e30f;
        }

        // online softmax (rows owned by the 16 lanes sharing tq; width-16 shuffles)
        float p[4][4], alpha[4];
        #pragma unroll
        for (int i = 0; i < 4; i++) {
            float mx = fmaxf(fmaxf(s[i][0], s[i][1]), fmaxf(s[i][2], s[i][3]));
            #pragma unroll
            for (int off = 1; off < 16; off <<= 1)
                mx = fmaxf(mx, __shfl_xor(mx, off, 16));
            float mn = fmaxf(m_i[i], mx);
            float rs = 0.0f;
            #pragma unroll
            for (int j = 0; j < 4; j++) { p[i][j] = __expf(s[i][j] - mn); rs += p[i][j]; }
            #pragma unroll
            for (int off = 1; off < 16; off <<= 1)
                rs += __shfl_xor(rs, off, 16);
            alpha[i] = __expf(m_i[i] - mn);
            l_i[i] = l_i[i] * alpha[i] + rs;
            m_i[i] = mn;
        }

        __syncthreads();   // all waves done with Ks before P overwrites it
        #pragma unroll
        for (int i = 0; i < 4; i++) {
            *(float4*)&Ps[tq*4+i][tk*4] = make_float4(p[i][0], p[i][1], p[i][2], p[i][3]);
            #pragma unroll
            for (int j = 0; j < 4; j++) o_acc[i][j] *= alpha[i];
        }
        __syncthreads();   // P visible

        // O += P V  (thread: q-rows tq*4+i, d-cols tk*4+j)
        #pragma unroll
        for (int c = 0; c < 64; c += 4) {
            float4 pr[4], vr[4];
            #pragma unroll
            for (int i = 0; i < 4; i++) pr[i] = *(const float4*)&Ps[tq*4+i][c];
            #pragma unroll
            for (int cc = 0; cc < 4; cc++) vr[cc] = *(const float4*)&Vs[c+cc][tk*4];
            #pragma unroll
            for (int i = 0; i < 4; i++) {
                o_acc[i][0] += pr[i].x*vr[0].x + pr[i].y*vr[1].x + pr[i].z*vr[2].x + pr[i].w*vr[3].x;
                o_acc[i][1] += pr[i].x*vr[0].y + pr[i].y*vr[1].y + pr[i].z*vr[2].y + pr[i].w*vr[3].y;
                o_acc[i][2] += pr[i].x*vr[0].z + pr[i].y*vr[1].z + pr[i].z*vr[2].z + pr[i].w*vr[3].z;
                o_acc[i][3] += pr[i].x*vr[0].w + pr[i].y*vr[1].w + pr[i].z*vr[2].w + pr[i].w*vr[3].w;
            }
        }
    }

    #pragma unroll
    for (int i = 0; i < 4; i++) {
        float inv = 1.0f / l_i[i];
        *(float4*)(y + qbase + (size_t)(tq*4+i) * Cq + tk*4) =
            make_float4(o_acc[i][0]*inv, o_acc[i][1]*inv, o_acc[i][2]*inv, o_acc[i][3]*inv);
    }
}

// ---------------------------------------------------------------------------
// Router: one wave per token, fp32 (precision-critical: top-k selection).
// ---------------------------------------------------------------------------
__global__ __launch_bounds__(64) void router_k(const float* __restrict__ hn,
                                               const float* __restrict__ rw,
                                               float* __restrict__ gate) {
    int tkn = blockIdx.x;
    int lane = threadIdx.x;
    float acc[Eq] = {};
    for (int it = 0; it < Cq / 64; it++) {
        float hv = hn[(size_t)tkn * Cq + it * 64 + lane];
        #pragma unroll
        for (int e = 0; e < Eq; e++)
            acc[e] = fmaf(hv, rw[e * Cq + it * 64 + lane], acc[e]);
    }
    #pragma unroll
    for (int e = 0; e < Eq; e++) {
        #pragma unroll
        for (int off = 32; off; off >>= 1) acc[e] += __shfl_xor(acc[e], off);
    }
    int i0 = 0;
    #pragma unroll
    for (int e = 1; e < Eq; e++) if (acc[e] > acc[i0]) i0 = e;
    int i1 = (i0 == 0) ? 1 : 0;
    #pragma unroll
    for (int e = 0; e < Eq; e++)
        if (e != i0 && acc[e] > acc[i1]) i1 = e;
    float p1 = __expf(acc[i1] - acc[i0]);
    float g0 = 1.0f / (1.0f + p1);
    float g1 = p1 / (1.0f + p1);
    if (lane < Eq)
        gate[(size_t)tkn * Eq + lane] = (lane == i0) ? g0 : ((lane == i1) ? g1 : 0.0f);
}

// ---------------------------------------------------------------------------
// fp32 -> bf16 conversion, two arrays per launch (blockIdx.y selects).
// ---------------------------------------------------------------------------
__global__ __launch_bounds__(256) void cvt2_k(const float* __restrict__ s0, ushort_t* __restrict__ d0,
                                              const float* __restrict__ s1, ushort_t* __restrict__ d1,
                                              int n) {
    int i = (blockIdx.x * 256 + threadIdx.x) * 4;
    const float* s = blockIdx.y ? s1 : s0;
    ushort_t* d = blockIdx.y ? d1 : d0;
    if (i < n) {
        float4 f = *(const float4*)(s + i);
        ushort4 o = make_ushort4(f2bf(f.x), f2bf(f.y), f2bf(f.z), f2bf(f.w));
        *(ushort4*)(d + i) = o;
    }
}

// ---------------------------------------------------------------------------
// MoE up-projection, bf16 MFMA, fused SwiGLU: gb = bf16(silu(A@W1^T) * (A@W3^T))
// 128x128 tile, BK=32, 256 threads (4 waves as 2x2 of 64x64), dual accumulators.
// A [M,K] bf16, W1/W3 [N,K] bf16. Verified gfx950 layouts:
//   A/B frag: [lane&15][(lane>>4)*8+j]; C/D: row=(lane>>4)*4+reg, col=lane&15.
// ---------------------------------------------------------------------------
__global__ __launch_bounds__(256, 2) void gemm_w13(const ushort_t* __restrict__ A,
                                                   const ushort_t* __restrict__ W1,
                                                   const ushort_t* __restrict__ W3,
                                                   ushort_t* __restrict__ gb,
                                                   int M, int N, int K) {
    __shared__ ushort_t As[128 * 32];
    __shared__ ushort_t B1s[128 * 32];
    __shared__ ushort_t B3s[128 * 32];
    int tid = threadIdx.x;
    int wave = tid >> 6, lane = tid & 63;
    int wm = wave >> 1, wn = wave & 1;
    int bx = blockIdx.x, by = blockIdx.y;

    const ushort_t* Ab  = A  + (size_t)(by * 128) * K;
    const ushort_t* W1b = W1 + (size_t)(bx * 128) * K;
    const ushort_t* W3b = W3 + (size_t)(bx * 128) * K;

    int srow = tid >> 2;             // 0..63
    int schunk = (tid & 3) * 8;      // bf16 elems (16B chunks)

    f32x4v acc1[4][4], acc3[4][4];
    #pragma unroll
    for (int i = 0; i < 4; i++)
        #pragma unroll
        for (int j = 0; j < 4; j++)
            #pragma unroll
            for (int r = 0; r < 4; r++) { acc1[i][j][r] = 0.0f; acc3[i][j][r] = 0.0f; }

    for (int k0 = 0; k0 < K; k0 += 32) {
        size_t go0 = (size_t)srow * K + k0 + schunk;
        size_t go1 = (size_t)(srow + 64) * K + k0 + schunk;
        int lo0 = srow * 32 + schunk;
        int lo1 = (srow + 64) * 32 + schunk;
        stage16(Ab  + go0, As  + lo0);
        stage16(Ab  + go1, As  + lo1);
        stage16(W1b + go0, B1s + lo0);
        stage16(W1b + go1, B1s + lo1);
        stage16(W3b + go0, B3s + lo0);
        stage16(W3b + go1, B3s + lo1);
        __syncthreads();

        int fr = lane & 15, fk = (lane >> 4) * 8;
        bf16x8 af[4], b1f[4], b3f[4];
        #pragma unroll
        for (int mi = 0; mi < 4; mi++)
            af[mi] = *(const bf16x8*)&As[(wm*64 + mi*16 + fr) * 32 + fk];
        #pragma unroll
        for (int ni = 0; ni < 4; ni++) {
            b1f[ni] = *(const bf16x8*)&B1s[(wn*64 + ni*16 + fr) * 32 + fk];
            b3f[ni] = *(const bf16x8*)&B3s[(wn*64 + ni*16 + fr) * 32 + fk];
        }
        #pragma unroll
        for (int mi = 0; mi < 4; mi++)
            #pragma unroll
            for (int ni = 0; ni < 4; ni++) {
                acc1[mi][ni] = __builtin_amdgcn_mfma_f32_16x16x32_bf16(af[mi], b1f[ni], acc1[mi][ni], 0, 0, 0);
                acc3[mi][ni] = __builtin_amdgcn_mfma_f32_16x16x32_bf16(af[mi], b3f[ni], acc3[mi][ni], 0, 0, 0);
            }
        __syncthreads();
    }

    int cr = (lane >> 4) * 4;
    int cc = lane & 15;
    #pragma unroll
    for (int mi = 0; mi < 4; mi++)
        #pragma unroll
        for (int ni = 0; ni < 4; ni++)
            #pragma unroll
            for (int r = 0; r < 4; r++) {
                int row = by*128 + wm*64 + mi*16 + cr + r;
                int col = bx*128 + wn*64 + ni*16 + cc;
                size_t off = (size_t)row * N + col;
                gb[off] = f2bf(silu_f(acc1[mi][ni][r]) * acc3[mi][ni][r]);
            }
}

// ---------------------------------------------------------------------------
// MoE down-projection, bf16 MFMA: Cf += gate[row*8+e] * (A@W2^T)
// ---------------------------------------------------------------------------
__global__ __launch_bounds__(256, 2) void gemm_w2(const ushort_t* __restrict__ A,
                                                  const ushort_t* __restrict__ W,
                                                  float* __restrict__ Cf,
                                                  const float* __restrict__ gate,
                                                  int M, int N, int K, int e) {
    __shared__ ushort_t As[128 * 32];
    __shared__ ushort_t Bs[128 * 32];
    int tid = threadIdx.x;
    int wave = tid >> 6, lane = tid & 63;
    int wm = wave >> 1, wn = wave & 1;
    int bx = blockIdx.x, by = blockIdx.y;

    const ushort_t* Ab = A + (size_t)(by * 128) * K;
    const ushort_t* Wb = W + (size_t)(bx * 128) * K;

    int srow = tid >> 2;
    int schunk = (tid & 3) * 8;

    f32x4v acc[4][4];
    #pragma unroll
    for (int i = 0; i < 4; i++)
        #pragma unroll
        for (int j = 0; j < 4; j++)
            #pragma unroll
            for (int r = 0; r < 4; r++) acc[i][j][r] = 0.0f;

    for (int k0 = 0; k0 < K; k0 += 32) {
        size_t go0 = (size_t)srow * K + k0 + schunk;
        size_t go1 = (size_t)(srow + 64) * K + k0 + schunk;
        int lo0 = srow * 32 + schunk;
        int lo1 = (srow + 64) * 32 + schunk;
        stage16(Ab + go0, As + lo0);
        stage16(Ab + go1, As + lo1);
        stage16(Wb + go0, Bs + lo0);
        stage16(Wb + go1, Bs + lo1);
        __syncthreads();

        int fr = lane & 15, fk = (lane >> 4) * 8;
        bf16x8 af[4], bf_[4];
        #pragma unroll
        for (int mi = 0; mi < 4; mi++)
            af[mi] = *(const bf16x8*)&As[(wm*64 + mi*16 + fr) * 32 + fk];
        #pragma unroll
        for (int ni = 0; ni < 4; ni++)
            bf_[ni] = *(const bf16x8*)&Bs[(wn*64 + ni*16 + fr) * 32 + fk];
        #pragma unroll
        for (int mi = 0; mi < 4; mi++)
            #pragma unroll
            for (int ni = 0; ni < 4; ni++)
                acc[mi][ni] = __builtin_amdgcn_mfma_f32_16x16x32_bf16(af[mi], bf_[ni], acc[mi][ni], 0, 0, 0);
        __syncthreads();
    }

    int cr = (lane >> 4) * 4;
    int cc = lane & 15;
    #pragma unroll
    for (int mi = 0; mi < 4; mi++)
        #pragma unroll
        for (int ni = 0; ni < 4; ni++)
            #pragma unroll
            for (int r = 0; r < 4; r++) {
                int row = by*128 + wm*64 + mi*16 + cr + r;
                int col = bx*128 + wn*64 + ni*16 + cc;
                size_t off = (size_t)row * N + col;
                Cf[off] += gate[(size_t)row * Eq + e] * acc[mi][ni][r];
            }
}

// ---------------------------------------------------------------------------
// Launch
// ---------------------------------------------------------------------------
extern "C" void kernel_launch(void* const* d_in, const int* in_sizes, int n_in,
                              void* d_out, int out_size, void* d_ws, size_t ws_size,
                              hipStream_t stream) {
    (void)in_sizes; (void)n_in; (void)out_size; (void)ws_size;

    const float* x     = (const float*)d_in[0];
    const float* ropec = (const float*)d_in[1];
    const float* ropes = (const float*)d_in[2];
    const float* anw   = (const float*)d_in[3];
    const float* q_w   = (const float*)d_in[4];
    const float* k_w   = (const float*)d_in[5];
    const float* v_w   = (const float*)d_in[6];
    const float* o_w   = (const float*)d_in[7];
    const float* fnw   = (const float*)d_in[8];
    const float* rtw   = (const float*)d_in[9];
    const float* w1    = (const float*)d_in[10];
    const float* w2    = (const float*)d_in[11];
    const float* w3    = (const float*)d_in[12];
    float* out = (float*)d_out;

    // workspace layout (float units; high-water 17301504 floats = 69.2 MB)
    const size_t F1 = 4194304;              // 4096*1024
    float* ws = (float*)d_ws;
    float* h    = ws;                       // [0,4M)   h -> later y
    float* qb   = ws + F1;                  // [4M,8M)  q -> later hn
    float* kb   = ws + 2*F1;                // [8M,12M) k -> later gate+hnb
    float* vb   = ws + 3*F1;                // [12M,16M) v -> later gbb
    float* yb   = h;
    float* hn   = qb;
    float* gate = kb;                                        // 32768 floats
    ushort_t* hnb = (ushort_t*)(ws + 2*F1 + 32768);          // 4M bf16
    ushort_t* gbb = (ushort_t*)(ws + 3*F1);                  // 4096x1536 bf16
    ushort_t* wb1 = (ushort_t*)(ws + 15728640);              // expert wbuf slot A
    ushort_t* wb3 = wb1 + 1572864;                           // expert wbuf slot B

    const int M = NTOK;

    // 1. attn rmsnorm (fp32)
    hipLaunchKernelGGL(rmsnorm_k, dim3(M), dim3(256), 0, stream, x, anw, h);

    // 2-4. Q,K,V projections (fp32 — router-safe path)
    hipLaunchKernelGGL(gemm_bt, dim3(Cq/64, M/64), dim3(256), 0, stream,
                       h, q_w, qb, M, Cq, Cq, (const float*)nullptr, 0);
    hipLaunchKernelGGL(gemm_bt, dim3(Cq/64, M/64), dim3(256), 0, stream,
                       h, k_w, kb, M, Cq, Cq, (const float*)nullptr, 0);
    hipLaunchKernelGGL(gemm_bt, dim3(Cq/64, M/64), dim3(256), 0, stream,
                       h, v_w, vb, M, Cq, Cq, (const float*)nullptr, 0);

    // 5. RoPE
    hipLaunchKernelGGL(rope_k, dim3((2 * NTOK * 512) / 256), dim3(256), 0, stream,
                       qb, kb, ropec, ropes);

    // 6. flash attention -> y (= h region)
    hipLaunchKernelGGL(attn_flash, dim3(Tq/64, Bq*Hq), dim3(256), 0, stream,
                       qb, kb, vb, yb);

    // 7. O projection + residual -> out (fp32)
    hipLaunchKernelGGL(gemm_bt, dim3(Cq/64, M/64), dim3(256), 0, stream,
                       yb, o_w, out, M, Cq, Cq, x, 1);

    // 8. ffn rmsnorm -> hn (fp32, feeds router)
    hipLaunchKernelGGL(rmsnorm_k, dim3(M), dim3(256), 0, stream, out, fnw, hn);

    // 9. router -> gate (fp32)
    hipLaunchKernelGGL(router_k, dim3(M), dim3(64), 0, stream, hn, rtw, gate);

    // 10. hn -> bf16
    hipLaunchKernelGGL(cvt2_k, dim3(2048, 2), dim3(256), 0, stream,
                       hn, hnb, hn + 2097152, hnb + 2097152, 2097152);

    // 11. MoE, dense over experts, bf16 MFMA
    const int WE = HDq * Cq;                 // 1572864 elems per expert matrix
    for (int e = 0; e < Eq; e++) {
        // convert w1[e], w3[e]
        hipLaunchKernelGGL(cvt2_k, dim3(1536, 2), dim3(256), 0, stream,
                           w1 + (size_t)e * WE, wb1, w3 + (size_t)e * WE, wb3, WE);
        // gbb = silu(hn@w1^T) * (hn@w3^T)
        hipLaunchKernelGGL(gemm_w13, dim3(HDq/128, M/128), dim3(256), 0, stream,
                           hnb, wb1, wb3, gbb, M, HDq, Cq);
        // convert w2[e] (overwrites wb1+wb3 slots)
        hipLaunchKernelGGL(cvt2_k, dim3(768, 2), dim3(256), 0, stream,
                           w2 + (size_t)e * WE, wb1,
                           w2 + (size_t)e * WE + WE/2, wb1 + WE/2, WE/2);
        // out += gate[:,e] * (gbb @ w2^T)
        hipLaunchKernelGGL(gemm_w2, dim3(Cq/128, M/128), dim3(256), 0, stream,
                           gbb, wb1, out, gate, M, Cq, HDq, e);
    }
}

// Round 3
// 1666.653 us; speedup vs baseline: 6.2993x; 1.6065x over previous
//
#include <hip/hip_runtime.h>
#include <hip/hip_bf16.h>
#include <math.h>

// Problem constants
#define Bq 2
#define Tq 2048
#define Cq 1024
#define Hq 16
#define Dq 64
#define Eq 8
#define HDq 1536
#define NTOK (Bq*Tq)        // 4096 tokens

typedef unsigned short u16;
typedef unsigned short ushort_t;
typedef _Float16 f16;
typedef __bf16 bf16x8 __attribute__((ext_vector_type(8)));
typedef _Float16 f16x8 __attribute__((ext_vector_type(8)));
typedef float f32x4v __attribute__((ext_vector_type(4)));

__device__ __forceinline__ float silu_f(float a) {
    return a / (1.0f + __expf(-a));
}

// fp32 -> bf16 RTNE
__device__ __forceinline__ ushort_t f2bf(float f) {
    union { float f; unsigned u; } a; a.f = f;
    unsigned r = a.u + 0x7fffu + ((a.u >> 16) & 1u);
    return (ushort_t)(r >> 16);
}

__device__ __forceinline__ u16 f16bits(f16 h) {
    union { f16 f; u16 u; } a; a.f = h; return a.u;
}

// async global->LDS, 16B per lane
__device__ __forceinline__ void stage16(const void* g, void* l) {
#if __has_builtin(__builtin_amdgcn_global_load_lds)
    __builtin_amdgcn_global_load_lds(
        (const __attribute__((address_space(1))) unsigned int*)g,
        (__attribute__((address_space(3))) unsigned int*)l, 16, 0, 0);
#else
    *(uint4*)l = *(const uint4*)g;
#endif
}

// ---------------------------------------------------------------------------
// RMSNorm (fp32): one block per row of C=1024.
// ---------------------------------------------------------------------------
__global__ __launch_bounds__(256) void rmsnorm_k(const float* __restrict__ x,
                                                 const float* __restrict__ w,
                                                 float* __restrict__ out) {
    int row = blockIdx.x;
    int tid = threadIdx.x;
    const float* xr = x + (size_t)row * Cq;
    float4 v = *(const float4*)(xr + tid * 4);
    float ss = v.x*v.x + v.y*v.y + v.z*v.z + v.w*v.w;
    #pragma unroll
    for (int off = 32; off; off >>= 1) ss += __shfl_xor(ss, off);
    __shared__ float red[4];
    if ((tid & 63) == 0) red[tid >> 6] = ss;
    __syncthreads();
    float tot = red[0] + red[1] + red[2] + red[3];
    float scale = rsqrtf(tot * (1.0f / (float)Cq) + 1e-6f);
    float4 wv = *(const float4*)(w + tid * 4);
    float4 o;
    o.x = v.x * wv.x * scale;
    o.y = v.y * wv.y * scale;
    o.z = v.z * wv.z * scale;
    o.w = v.w * wv.w * scale;
    *(float4*)(out + (size_t)row * Cq + tid * 4) = o;
}

// ---------------------------------------------------------------------------
// fp32 tiled GEMM (QKV / O-proj): C[M,N] = A[M,K] @ W[N,K]^T
// mode 0: C = acc ; mode 1: C = aux + acc. Router-safe fp32 path.
// ---------------------------------------------------------------------------
__global__ __launch_bounds__(256) void gemm_bt(const float* __restrict__ A,
                                               const float* __restrict__ W,
                                               float* __restrict__ C,
                                               int M, int N, int K,
                                               const float* __restrict__ aux,
                                               int mode) {
    __shared__ float As[16][68];
    __shared__ float Ws[16][68];
    int tid = threadIdx.x;
    int bx = blockIdx.x;
    int by = blockIdx.y;

    int lrow = tid >> 2;
    int lk4  = (tid & 3) * 4;

    const float* Ab = A + (size_t)(by * 64) * K;
    const float* Wb = W + (size_t)(bx * 64) * K;

    float acc[4][4] = {};

    for (int k0 = 0; k0 < K; k0 += 16) {
        float4 av = *(const float4*)(Ab + (size_t)lrow * K + k0 + lk4);
        float4 wv = *(const float4*)(Wb + (size_t)lrow * K + k0 + lk4);
        As[lk4 + 0][lrow] = av.x;
        As[lk4 + 1][lrow] = av.y;
        As[lk4 + 2][lrow] = av.z;
        As[lk4 + 3][lrow] = av.w;
        Ws[lk4 + 0][lrow] = wv.x;
        Ws[lk4 + 1][lrow] = wv.y;
        Ws[lk4 + 2][lrow] = wv.z;
        Ws[lk4 + 3][lrow] = wv.w;
        __syncthreads();
        int ty4 = (tid >> 4) * 4;
        int tx4 = (tid & 15) * 4;
        #pragma unroll
        for (int kk = 0; kk < 16; kk++) {
            float4 a = *(const float4*)&As[kk][ty4];
            float4 b = *(const float4*)&Ws[kk][tx4];
            float ar[4] = {a.x, a.y, a.z, a.w};
            float br[4] = {b.x, b.y, b.z, b.w};
            #pragma unroll
            for (int i = 0; i < 4; i++)
                #pragma unroll
                for (int j = 0; j < 4; j++)
                    acc[i][j] = fmaf(ar[i], br[j], acc[i][j]);
        }
        __syncthreads();
    }

    int m0 = by * 64 + (tid >> 4) * 4;
    int n0 = bx * 64 + (tid & 15) * 4;
    #pragma unroll
    for (int i = 0; i < 4; i++) {
        size_t off = (size_t)(m0 + i) * N + n0;
        if (mode == 0) {
            *(float4*)(C + off) = make_float4(acc[i][0], acc[i][1], acc[i][2], acc[i][3]);
        } else {
            float4 r = *(const float4*)(aux + off);
            *(float4*)(C + off) = make_float4(acc[i][0] + r.x, acc[i][1] + r.y,
                                              acc[i][2] + r.z, acc[i][3] + r.w);
        }
    }
}

// ---------------------------------------------------------------------------
// RoPE + split-fp16: src fp32 [4096][1024] -> (hh, hl) u16 arrays, same layout.
// scale applied after rope (0.125 for q, 1.0 for k).
// ---------------------------------------------------------------------------
__global__ __launch_bounds__(256) void ropesplit_k(const float* __restrict__ src,
                                                   u16* __restrict__ hh,
                                                   u16* __restrict__ hl,
                                                   const float* __restrict__ cosb,
                                                   const float* __restrict__ sinb,
                                                   float scale) {
    int row = blockIdx.x;
    int tid = threadIdx.x;
    int t = row & (Tq - 1);
    #pragma unroll
    for (int pi = 0; pi < 2; pi++) {
        int p = tid * 2 + pi;          // 0..511
        int h = p >> 5, d = p & 31;
        size_t i0 = (size_t)row * Cq + h * Dq + d;
        float a = src[i0], b = src[i0 + 32];
        float c0 = cosb[t * Dq + d],      s0 = sinb[t * Dq + d];
        float c1 = cosb[t * Dq + d + 32], s1 = sinb[t * Dq + d + 32];
        float o0 = (a * c0 - b * s0) * scale;
        float o1 = (b * c1 + a * s1) * scale;
        f16 h0 = (f16)o0; f16 l0 = (f16)(o0 - (float)h0);
        f16 h1 = (f16)o1; f16 l1 = (f16)(o1 - (float)h1);
        hh[i0]      = f16bits(h0);
        hl[i0]      = f16bits(l0);
        hh[i0 + 32] = f16bits(h1);
        hl[i0 + 32] = f16bits(l1);
    }
}

// ---------------------------------------------------------------------------
// V transpose + split: v fp32 [b][t][h*64+d] -> vth/vtl u16 [bh][d][t] (d-major)
// so attention's PV B-operand stages with coalesced contiguous-key loads.
// ---------------------------------------------------------------------------
__global__ __launch_bounds__(256) void vtrans_k(const float* __restrict__ v,
                                                u16* __restrict__ vth,
                                                u16* __restrict__ vtl) {
    __shared__ u16 Th[64 * 72];
    __shared__ u16 Tl[64 * 72];
    int tc = blockIdx.x;           // t-chunk 0..31
    int bh = blockIdx.y;           // 0..31
    int b = bh >> 4, h = bh & 15;
    int tid = threadIdx.x;
    int tr = tid >> 2;             // token-row 0..63
    int dc = (tid & 3) * 16;       // d-chunk
    size_t gin = ((size_t)(b * Tq + tc * 64 + tr)) * Cq + h * Dq + dc;
    #pragma unroll
    for (int i = 0; i < 16; i += 4) {
        float4 f = *(const float4*)(v + gin + i);
        float fv[4] = {f.x, f.y, f.z, f.w};
        #pragma unroll
        for (int j = 0; j < 4; j++) {
            f16 hi = (f16)fv[j];
            f16 lo = (f16)(fv[j] - (float)hi);
            Th[(dc + i + j) * 72 + tr] = f16bits(hi);
            Tl[(dc + i + j) * 72 + tr] = f16bits(lo);
        }
    }
    __syncthreads();
    int dr = tid >> 2;             // d-row 0..63
    int cc = (tid & 3) * 16;       // t-col chunk
    size_t gout = ((size_t)(bh * 64 + dr)) * Tq + tc * 64 + cc;
    *(uint4*)(vth + gout)     = *(uint4*)(Th + dr * 72 + cc);
    *(uint4*)(vth + gout + 8) = *(uint4*)(Th + dr * 72 + cc + 8);
    *(uint4*)(vtl + gout)     = *(uint4*)(Tl + dr * 72 + cc);
    *(uint4*)(vtl + gout + 8) = *(uint4*)(Tl + dr * 72 + cc + 8);
}

// ---------------------------------------------------------------------------
// Flash attention, split-fp16 MFMA (16x16x32_f16, 3-term: qh*kh+qh*kl+ql*kh).
// Block = 64 q-rows x 64 keys, 4 waves (wave = 16 q-rows). Grid (qt=32, bh=32).
// LDS planes stride 72 u16 (144 B, keeps b128 alignment, spreads banks).
// A/B frag: [lane&15][(lane>>4)*8+j]; C/D: row=(lane>>4)*4+reg, col=lane&15.
// ---------------------------------------------------------------------------
#define AST 72
__global__ __launch_bounds__(256, 2) void attn_f16(const u16* __restrict__ qh_g,
                                                   const u16* __restrict__ ql_g,
                                                   const u16* __restrict__ kh_g,
                                                   const u16* __restrict__ kl_g,
                                                   const u16* __restrict__ vth_g,
                                                   const u16* __restrict__ vtl_g,
                                                   float* __restrict__ y) {
    __shared__ u16 Qh[64*AST], Ql[64*AST];
    __shared__ u16 Kh[64*AST], Kl[64*AST];
    __shared__ u16 Vh[64*AST], Vl[64*AST];
    __shared__ u16 Ph[64*AST], Pl[64*AST];

    int qt = blockIdx.x;           // q-tile
    int bh = blockIdx.y;
    int b = bh >> 4, h = bh & 15;
    int tid = threadIdx.x;
    int wv = tid >> 6, lane = tid & 63;
    int fr = lane & 15, fg = lane >> 4;
    int sr = tid >> 2, sc = (tid & 3) * 16;

    // stage Q once
    {
        size_t g = ((size_t)(b * Tq + qt * 64 + sr)) * Cq + h * Dq + sc;
        *(uint4*)(Qh + sr*AST + sc)     = *(const uint4*)(qh_g + g);
        *(uint4*)(Qh + sr*AST + sc + 8) = *(const uint4*)(qh_g + g + 8);
        *(uint4*)(Ql + sr*AST + sc)     = *(const uint4*)(ql_g + g);
        *(uint4*)(Ql + sr*AST + sc + 8) = *(const uint4*)(ql_g + g + 8);
    }

    f32x4v acc_o[4];
    float m_i[4], l_i[4];
    #pragma unroll
    for (int i = 0; i < 4; i++) {
        m_i[i] = -1e30f; l_i[i] = 0.0f;
        #pragma unroll
        for (int r = 0; r < 4; r++) acc_o[i][r] = 0.0f;
    }

    int aoff = (wv * 16 + fr) * AST + fg * 8;   // A-frag base (Q and P)

    for (int kt = 0; kt <= qt; kt++) {
        __syncthreads();   // prev PV done; safe to restage K/V
        {
            size_t kg = ((size_t)(b * Tq + kt * 64 + sr)) * Cq + h * Dq + sc;
            size_t vg = ((size_t)(bh * 64 + sr)) * Tq + kt * 64 + sc;
            *(uint4*)(Kh + sr*AST + sc)     = *(const uint4*)(kh_g + kg);
            *(uint4*)(Kh + sr*AST + sc + 8) = *(const uint4*)(kh_g + kg + 8);
            *(uint4*)(Kl + sr*AST + sc)     = *(const uint4*)(kl_g + kg);
            *(uint4*)(Kl + sr*AST + sc + 8) = *(const uint4*)(kl_g + kg + 8);
            *(uint4*)(Vh + sr*AST + sc)     = *(const uint4*)(vth_g + vg);
            *(uint4*)(Vh + sr*AST + sc + 8) = *(const uint4*)(vth_g + vg + 8);
            *(uint4*)(Vl + sr*AST + sc)     = *(const uint4*)(vtl_g + vg);
            *(uint4*)(Vl + sr*AST + sc + 8) = *(const uint4*)(vtl_g + vg + 8);
        }
        __syncthreads();

        // ---- S = Q K^T (split 3-term) ----
        f16x8 aqh0 = *(const f16x8*)(const void*)(Qh + aoff);
        f16x8 aqh1 = *(const f16x8*)(const void*)(Qh + aoff + 32);
        f16x8 aql0 = *(const f16x8*)(const void*)(Ql + aoff);
        f16x8 aql1 = *(const f16x8*)(const void*)(Ql + aoff + 32);

        f32x4v s[4];
        #pragma unroll
        for (int ni = 0; ni < 4; ni++) {
            int boff = (ni * 16 + fr) * AST + fg * 8;
            f16x8 bh0 = *(const f16x8*)(const void*)(Kh + boff);
            f16x8 bh1 = *(const f16x8*)(const void*)(Kh + boff + 32);
            f16x8 bl0 = *(const f16x8*)(const void*)(Kl + boff);
            f16x8 bl1 = *(const f16x8*)(const void*)(Kl + boff + 32);
            f32x4v t;
            #pragma unroll
            for (int r = 0; r < 4; r++) t[r] = 0.0f;
            t = __builtin_amdgcn_mfma_f32_16x16x32_f16(aqh0, bh0, t, 0, 0, 0);
            t = __builtin_amdgcn_mfma_f32_16x16x32_f16(aqh1, bh1, t, 0, 0, 0);
            t = __builtin_amdgcn_mfma_f32_16x16x32_f16(aqh0, bl0, t, 0, 0, 0);
            t = __builtin_amdgcn_mfma_f32_16x16x32_f16(aqh1, bl1, t, 0, 0, 0);
            t = __builtin_amdgcn_mfma_f32_16x16x32_f16(aql0, bh0, t, 0, 0, 0);
            t = __builtin_amdgcn_mfma_f32_16x16x32_f16(aql1, bh1, t, 0, 0, 0);
            s[ni] = t;
        }

        // causal mask (diagonal tile only)
        if (kt == qt) {
            #pragma unroll
            for (int ni = 0; ni < 4; ni++) {
                int col = ni * 16 + fr;
                #pragma unroll
                for (int r = 0; r < 4; r++) {
                    int row = wv * 16 + fg * 4 + r;
                    if (col > row) s[ni][r] = -1e30f;
                }
            }
        }

        // ---- online softmax (rows = fg*4+r within wave's 16) ----
        float p[4][4];
        #pragma unroll
        for (int r = 0; r < 4; r++) {
            float mx = fmaxf(fmaxf(s[0][r], s[1][r]), fmaxf(s[2][r], s[3][r]));
            #pragma unroll
            for (int off = 1; off < 16; off <<= 1)
                mx = fmaxf(mx, __shfl_xor(mx, off, 16));
            float mn = fmaxf(m_i[r], mx);
            float rs = 0.0f;
            #pragma unroll
            for (int ni = 0; ni < 4; ni++) {
                p[ni][r] = __expf(s[ni][r] - mn);
                rs += p[ni][r];
            }
            #pragma unroll
            for (int off = 1; off < 16; off <<= 1)
                rs += __shfl_xor(rs, off, 16);
            float alpha = __expf(m_i[r] - mn);
            l_i[r] = l_i[r] * alpha + rs;
            m_i[r] = mn;
            #pragma unroll
            for (int ni = 0; ni < 4; ni++) acc_o[ni][r] *= alpha;
        }

        // ---- write P (split) to LDS; rows are wave-private ----
        #pragma unroll
        for (int ni = 0; ni < 4; ni++) {
            #pragma unroll
            for (int r = 0; r < 4; r++) {
                int off = (wv * 16 + fg * 4 + r) * AST + ni * 16 + fr;
                f16 ph = (f16)p[ni][r];
                f16 pl = (f16)(p[ni][r] - (float)ph);
                Ph[off] = f16bits(ph);
                Pl[off] = f16bits(pl);
            }
        }

        // ---- O += P V (split 3-term) ----
        f16x8 aph0 = *(const f16x8*)(const void*)(Ph + aoff);
        f16x8 aph1 = *(const f16x8*)(const void*)(Ph + aoff + 32);
        f16x8 apl0 = *(const f16x8*)(const void*)(Pl + aoff);
        f16x8 apl1 = *(const f16x8*)(const void*)(Pl + aoff + 32);
        #pragma unroll
        for (int ni = 0; ni < 4; ni++) {
            int boff = (ni * 16 + fr) * AST + fg * 8;
            f16x8 bvh0 = *(const f16x8*)(const void*)(Vh + boff);
            f16x8 bvh1 = *(const f16x8*)(const void*)(Vh + boff + 32);
            f16x8 bvl0 = *(const f16x8*)(const void*)(Vl + boff);
            f16x8 bvl1 = *(const f16x8*)(const void*)(Vl + boff + 32);
            f32x4v t = acc_o[ni];
            t = __builtin_amdgcn_mfma_f32_16x16x32_f16(aph0, bvh0, t, 0, 0, 0);
            t = __builtin_amdgcn_mfma_f32_16x16x32_f16(aph1, bvh1, t, 0, 0, 0);
            t = __builtin_amdgcn_mfma_f32_16x16x32_f16(aph0, bvl0, t, 0, 0, 0);
            t = __builtin_amdgcn_mfma_f32_16x16x32_f16(aph1, bvl1, t, 0, 0, 0);
            t = __builtin_amdgcn_mfma_f32_16x16x32_f16(apl0, bvh0, t, 0, 0, 0);
            t = __builtin_amdgcn_mfma_f32_16x16x32_f16(apl1, bvh1, t, 0, 0, 0);
            acc_o[ni] = t;
        }
    }

    // epilogue: y[row][h*64+col] = O / l
    #pragma unroll
    for (int r = 0; r < 4; r++) {
        float inv = 1.0f / l_i[r];
        int row = qt * 64 + wv * 16 + fg * 4 + r;
        size_t base = ((size_t)(b * Tq + row)) * Cq + h * Dq + fr;
        #pragma unroll
        for (int ni = 0; ni < 4; ni++)
            y[base + ni * 16] = acc_o[ni][r] * inv;
    }
}

// ---------------------------------------------------------------------------
// Router: one wave per token, fp32 (precision-critical top-k).
// ---------------------------------------------------------------------------
__global__ __launch_bounds__(64) void router_k(const float* __restrict__ hn,
                                               const float* __restrict__ rw,
                                               float* __restrict__ gate) {
    int tkn = blockIdx.x;
    int lane = threadIdx.x;
    float acc[Eq] = {};
    for (int it = 0; it < Cq / 64; it++) {
        float hv = hn[(size_t)tkn * Cq + it * 64 + lane];
        #pragma unroll
        for (int e = 0; e < Eq; e++)
            acc[e] = fmaf(hv, rw[e * Cq + it * 64 + lane], acc[e]);
    }
    #pragma unroll
    for (int e = 0; e < Eq; e++) {
        #pragma unroll
        for (int off = 32; off; off >>= 1) acc[e] += __shfl_xor(acc[e], off);
    }
    int i0 = 0;
    #pragma unroll
    for (int e = 1; e < Eq; e++) if (acc[e] > acc[i0]) i0 = e;
    int i1 = (i0 == 0) ? 1 : 0;
    #pragma unroll
    for (int e = 0; e < Eq; e++)
        if (e != i0 && acc[e] > acc[i1]) i1 = e;
    float p1 = __expf(acc[i1] - acc[i0]);
    float g0 = 1.0f / (1.0f + p1);
    float g1 = p1 / (1.0f + p1);
    if (lane < Eq)
        gate[(size_t)tkn * Eq + lane] = (lane == i0) ? g0 : ((lane == i1) ? g1 : 0.0f);
}

// ---------------------------------------------------------------------------
// fp32 -> bf16 conversion, two arrays per launch.
// ---------------------------------------------------------------------------
__global__ __launch_bounds__(256) void cvt2_k(const float* __restrict__ s0, ushort_t* __restrict__ d0,
                                              const float* __restrict__ s1, ushort_t* __restrict__ d1,
                                              int n) {
    int i = (blockIdx.x * 256 + threadIdx.x) * 4;
    const float* s = blockIdx.y ? s1 : s0;
    ushort_t* d = blockIdx.y ? d1 : d0;
    if (i < n) {
        float4 f = *(const float4*)(s + i);
        ushort4 o = make_ushort4(f2bf(f.x), f2bf(f.y), f2bf(f.z), f2bf(f.w));
        *(ushort4*)(d + i) = o;
    }
}

// ---------------------------------------------------------------------------
// MoE up-projection, bf16 MFMA, fused SwiGLU.
// ---------------------------------------------------------------------------
__global__ __launch_bounds__(256, 2) void gemm_w13(const ushort_t* __restrict__ A,
                                                   const ushort_t* __restrict__ W1,
                                                   const ushort_t* __restrict__ W3,
                                                   ushort_t* __restrict__ gb,
                                                   int M, int N, int K) {
    __shared__ ushort_t As[128 * 32];
    __shared__ ushort_t B1s[128 * 32];
    __shared__ ushort_t B3s[128 * 32];
    int tid = threadIdx.x;
    int wave = tid >> 6, lane = tid & 63;
    int wm = wave >> 1, wn = wave & 1;
    int bx = blockIdx.x, by = blockIdx.y;

    const ushort_t* Ab  = A  + (size_t)(by * 128) * K;
    const ushort_t* W1b = W1 + (size_t)(bx * 128) * K;
    const ushort_t* W3b = W3 + (size_t)(bx * 128) * K;

    int srow = tid >> 2;
    int schunk = (tid & 3) * 8;

    f32x4v acc1[4][4], acc3[4][4];
    #pragma unroll
    for (int i = 0; i < 4; i++)
        #pragma unroll
        for (int j = 0; j < 4; j++)
            #pragma unroll
            for (int r = 0; r < 4; r++) { acc1[i][j][r] = 0.0f; acc3[i][j][r] = 0.0f; }

    for (int k0 = 0; k0 < K; k0 += 32) {
        size_t go0 = (size_t)srow * K + k0 + schunk;
        size_t go1 = (size_t)(srow + 64) * K + k0 + schunk;
        int lo0 = srow * 32 + schunk;
        int lo1 = (srow + 64) * 32 + schunk;
        stage16(Ab  + go0, As  + lo0);
        stage16(Ab  + go1, As  + lo1);
        stage16(W1b + go0, B1s + lo0);
        stage16(W1b + go1, B1s + lo1);
        stage16(W3b + go0, B3s + lo0);
        stage16(W3b + go1, B3s + lo1);
        __syncthreads();

        int fr = lane & 15, fk = (lane >> 4) * 8;
        bf16x8 af[4], b1f[4], b3f[4];
        #pragma unroll
        for (int mi = 0; mi < 4; mi++)
            af[mi] = *(const bf16x8*)&As[(wm*64 + mi*16 + fr) * 32 + fk];
        #pragma unroll
        for (int ni = 0; ni < 4; ni++) {
            b1f[ni] = *(const bf16x8*)&B1s[(wn*64 + ni*16 + fr) * 32 + fk];
            b3f[ni] = *(const bf16x8*)&B3s[(wn*64 + ni*16 + fr) * 32 + fk];
        }
        #pragma unroll
        for (int mi = 0; mi < 4; mi++)
            #pragma unroll
            for (int ni = 0; ni < 4; ni++) {
                acc1[mi][ni] = __builtin_amdgcn_mfma_f32_16x16x32_bf16(af[mi], b1f[ni], acc1[mi][ni], 0, 0, 0);
                acc3[mi][ni] = __builtin_amdgcn_mfma_f32_16x16x32_bf16(af[mi], b3f[ni], acc3[mi][ni], 0, 0, 0);
            }
        __syncthreads();
    }

    int cr = (lane >> 4) * 4;
    int cc = lane & 15;
    #pragma unroll
    for (int mi = 0; mi < 4; mi++)
        #pragma unroll
        for (int ni = 0; ni < 4; ni++)
            #pragma unroll
            for (int r = 0; r < 4; r++) {
                int row = by*128 + wm*64 + mi*16 + cr + r;
                int col = bx*128 + wn*64 + ni*16 + cc;
                size_t off = (size_t)row * N + col;
                gb[off] = f2bf(silu_f(acc1[mi][ni][r]) * acc3[mi][ni][r]);
            }
}

// ---------------------------------------------------------------------------
// MoE down-projection, bf16 MFMA: Cf += gate[row*8+e] * (A@W2^T)
// ---------------------------------------------------------------------------
__global__ __launch_bounds__(256, 2) void gemm_w2(const ushort_t* __restrict__ A,
                                                  const ushort_t* __restrict__ W,
                                                  float* __restrict__ Cf,
                                                  const float* __restrict__ gate,
                                                  int M, int N, int K, int e) {
    __shared__ ushort_t As[128 * 32];
    __shared__ ushort_t Bs[128 * 32];
    int tid = threadIdx.x;
    int wave = tid >> 6, lane = tid & 63;
    int wm = wave >> 1, wn = wave & 1;
    int bx = blockIdx.x, by = blockIdx.y;

    const ushort_t* Ab = A + (size_t)(by * 128) * K;
    const ushort_t* Wb = W + (size_t)(bx * 128) * K;

    int srow = tid >> 2;
    int schunk = (tid & 3) * 8;

    f32x4v acc[4][4];
    #pragma unroll
    for (int i = 0; i < 4; i++)
        #pragma unroll
        for (int j = 0; j < 4; j++)
            #pragma unroll
            for (int r = 0; r < 4; r++) acc[i][j][r] = 0.0f;

    for (int k0 = 0; k0 < K; k0 += 32) {
        size_t go0 = (size_t)srow * K + k0 + schunk;
        size_t go1 = (size_t)(srow + 64) * K + k0 + schunk;
        int lo0 = srow * 32 + schunk;
        int lo1 = (srow + 64) * 32 + schunk;
        stage16(Ab + go0, As + lo0);
        stage16(Ab + go1, As + lo1);
        stage16(Wb + go0, Bs + lo0);
        stage16(Wb + go1, Bs + lo1);
        __syncthreads();

        int fr = lane & 15, fk = (lane >> 4) * 8;
        bf16x8 af[4], bf_[4];
        #pragma unroll
        for (int mi = 0; mi < 4; mi++)
            af[mi] = *(const bf16x8*)&As[(wm*64 + mi*16 + fr) * 32 + fk];
        #pragma unroll
        for (int ni = 0; ni < 4; ni++)
            bf_[ni] = *(const bf16x8*)&Bs[(wn*64 + ni*16 + fr) * 32 + fk];
        #pragma unroll
        for (int mi = 0; mi < 4; mi++)
            #pragma unroll
            for (int ni = 0; ni < 4; ni++)
                acc[mi][ni] = __builtin_amdgcn_mfma_f32_16x16x32_bf16(af[mi], bf_[ni], acc[mi][ni], 0, 0, 0);
        __syncthreads();
    }

    int cr = (lane >> 4) * 4;
    int cc = lane & 15;
    #pragma unroll
    for (int mi = 0; mi < 4; mi++)
        #pragma unroll
        for (int ni = 0; ni < 4; ni++)
            #pragma unroll
            for (int r = 0; r < 4; r++) {
                int row = by*128 + wm*64 + mi*16 + cr + r;
                int col = bx*128 + wn*64 + ni*16 + cc;
                size_t off = (size_t)row * N + col;
                Cf[off] += gate[(size_t)row * Eq + e] * acc[mi][ni][r];
            }
}

// ---------------------------------------------------------------------------
// Launch
// ---------------------------------------------------------------------------
extern "C" void kernel_launch(void* const* d_in, const int* in_sizes, int n_in,
                              void* d_out, int out_size, void* d_ws, size_t ws_size,
                              hipStream_t stream) {
    (void)in_sizes; (void)n_in; (void)out_size; (void)ws_size;

    const float* x     = (const float*)d_in[0];
    const float* ropec = (const float*)d_in[1];
    const float* ropes = (const float*)d_in[2];
    const float* anw   = (const float*)d_in[3];
    const float* q_w   = (const float*)d_in[4];
    const float* k_w   = (const float*)d_in[5];
    const float* v_w   = (const float*)d_in[6];
    const float* o_w   = (const float*)d_in[7];
    const float* fnw   = (const float*)d_in[8];
    const float* rtw   = (const float*)d_in[9];
    const float* w1    = (const float*)d_in[10];
    const float* w2    = (const float*)d_in[11];
    const float* w3    = (const float*)d_in[12];
    float* out = (float*)d_out;

    // workspace map (float units), high-water 16M floats = 64 MB:
    //  [0,4M)   : h (attn rmsnorm)   -> vth/vtl (u16) -> hn
    //  [4M,8M)  : q fp32             -> kh/kl (u16)   -> gbb (u16) [MoE]
    //  [8M,12M) : k fp32             -> y (fp32)      -> wb1/wb3 (u16) [MoE]
    //  [12M,16M): v fp32             -> qh/ql (u16)   -> gate + hnb
    const size_t F1 = 4194304;
    float* ws = (float*)d_ws;
    float* h   = ws;
    float* qb  = ws + F1;
    float* kb  = ws + 2 * F1;
    float* vb  = ws + 3 * F1;

    u16* vth = (u16*)ws;                       // 8 MB
    u16* vtl = (u16*)(ws + 2097152);           // 8 MB
    u16* qh  = (u16*)(ws + 3 * F1);            // 8 MB
    u16* ql  = (u16*)(ws + 3 * F1 + 2097152);
    u16* kh  = (u16*)(ws + F1);
    u16* kl  = (u16*)(ws + F1 + 2097152);
    float* yb = ws + 2 * F1;

    float* hn   = ws;
    float* gate = ws + 3 * F1;                               // 32768 fl
    ushort_t* hnb = (ushort_t*)(ws + 3 * F1 + 32768);        // 8 MB
    ushort_t* gbb = (ushort_t*)(ws + F1);                    // 12 MB
    ushort_t* wb1 = (ushort_t*)(ws + 2 * F1);                // 3 MB
    ushort_t* wb3 = wb1 + 1572864;                           // 3 MB

    const int M = NTOK;

    // 1. attn rmsnorm (fp32)
    hipLaunchKernelGGL(rmsnorm_k, dim3(M), dim3(256), 0, stream, x, anw, h);

    // 2-4. Q,K,V projections (fp32, router-safe)
    hipLaunchKernelGGL(gemm_bt, dim3(Cq/64, M/64), dim3(256), 0, stream,
                       h, q_w, qb, M, Cq, Cq, (const float*)nullptr, 0);
    hipLaunchKernelGGL(gemm_bt, dim3(Cq/64, M/64), dim3(256), 0, stream,
                       h, k_w, kb, M, Cq, Cq, (const float*)nullptr, 0);
    hipLaunchKernelGGL(gemm_bt, dim3(Cq/64, M/64), dim3(256), 0, stream,
                       h, v_w, vb, M, Cq, Cq, (const float*)nullptr, 0);

    // 5. V transpose+split (vb -> vth/vtl, into h region; h is dead now)
    hipLaunchKernelGGL(vtrans_k, dim3(32, 32), dim3(256), 0, stream, vb, vth, vtl);

    // 6. RoPE+split q (qb -> qh/ql, into vb region) then k (kb -> kh/kl, into qb region)
    hipLaunchKernelGGL(ropesplit_k, dim3(M), dim3(256), 0, stream,
                       qb, qh, ql, ropec, ropes, 0.125f);
    hipLaunchKernelGGL(ropesplit_k, dim3(M), dim3(256), 0, stream,
                       kb, kh, kl, ropec, ropes, 1.0f);

    // 7. flash attention (split-f16 MFMA) -> y (kb region)
    hipLaunchKernelGGL(attn_f16, dim3(Tq/64, Bq*Hq), dim3(256), 0, stream,
                       qh, ql, kh, kl, vth, vtl, yb);

    // 8. O projection + residual -> out (fp32)
    hipLaunchKernelGGL(gemm_bt, dim3(Cq/64, M/64), dim3(256), 0, stream,
                       yb, o_w, out, M, Cq, Cq, x, 1);

    // 9. ffn rmsnorm -> hn (fp32, feeds router)
    hipLaunchKernelGGL(rmsnorm_k, dim3(M), dim3(256), 0, stream, out, fnw, hn);

    // 10. router -> gate (fp32)
    hipLaunchKernelGGL(router_k, dim3(M), dim3(64), 0, stream, hn, rtw, gate);

    // 11. hn -> bf16
    hipLaunchKernelGGL(cvt2_k, dim3(2048, 2), dim3(256), 0, stream,
                       hn, hnb, hn + 2097152, hnb + 2097152, 2097152);

    // 12. MoE, dense over experts, bf16 MFMA
    const int WE = HDq * Cq;
    for (int e = 0; e < Eq; e++) {
        hipLaunchKernelGGL(cvt2_k, dim3(1536, 2), dim3(256), 0, stream,
                           w1 + (size_t)e * WE, wb1, w3 + (size_t)e * WE, wb3, WE);
        hipLaunchKernelGGL(gemm_w13, dim3(HDq/128, M/128), dim3(256), 0, stream,
                           hnb, wb1, wb3, gbb, M, HDq, Cq);
        hipLaunchKernelGGL(cvt2_k, dim3(768, 2), dim3(256), 0, stream,
                           w2 + (size_t)e * WE, wb1,
                           w2 + (size_t)e * WE + WE/2, wb1 + WE/2, WE/2);
        hipLaunchKernelGGL(gemm_w2, dim3(Cq/128, M/128), dim3(256), 0, stream,
                           gbb, wb1, out, gate, M, Cq, HDq, e);
    }
}

// Round 4
// 925.045 us; speedup vs baseline: 11.3495x; 1.8017x over previous
//
#include <hip/hip_runtime.h>
#include <hip/hip_bf16.h>
#include <math.h>

// Problem constants
#define Bq 2
#define Tq 2048
#define Cq 1024
#define Hq 16
#define Dq 64
#define Eq 8
#define HDq 1536
#define NTOK (Bq*Tq)        // 4096 tokens

typedef unsigned short u16;
typedef _Float16 f16;
typedef __bf16 bf16x8 __attribute__((ext_vector_type(8)));
typedef _Float16 f16x8 __attribute__((ext_vector_type(8)));
typedef float f32x4v __attribute__((ext_vector_type(4)));

#define MB(x) ((size_t)(x) * 262144)   // x MiB in floats

__device__ __forceinline__ float silu_f(float a) {
    return a / (1.0f + __expf(-a));
}
__device__ __forceinline__ u16 f2bf(float f) {
    union { float f; unsigned u; } a; a.f = f;
    unsigned r = a.u + 0x7fffu + ((a.u >> 16) & 1u);
    return (u16)(r >> 16);
}
__device__ __forceinline__ u16 f16bits(f16 h) {
    union { f16 f; u16 u; } a; a.f = h; return a.u;
}

// async global->LDS, 16B per lane (per-lane global addr OK; LDS side is
// wave-uniform base + lane*16)
__device__ __forceinline__ void stage16(const void* g, void* l) {
    __builtin_amdgcn_global_load_lds(
        (const __attribute__((address_space(1))) unsigned int*)g,
        (__attribute__((address_space(3))) unsigned int*)l, 16, 0, 0);
}

// ---------------------------------------------------------------------------
// RMSNorm -> split-f16 hi/lo (attention branch input)
// ---------------------------------------------------------------------------
__global__ __launch_bounds__(256) void rmsnorm_split_k(const float* __restrict__ x,
                                                       const float* __restrict__ w,
                                                       u16* __restrict__ hh,
                                                       u16* __restrict__ hl) {
    int row = blockIdx.x;
    int tid = threadIdx.x;
    const float* xr = x + (size_t)row * Cq;
    float4 v = *(const float4*)(xr + tid * 4);
    float ss = v.x*v.x + v.y*v.y + v.z*v.z + v.w*v.w;
    #pragma unroll
    for (int off = 32; off; off >>= 1) ss += __shfl_xor(ss, off);
    __shared__ float red[4];
    if ((tid & 63) == 0) red[tid >> 6] = ss;
    __syncthreads();
    float tot = red[0] + red[1] + red[2] + red[3];
    float scale = rsqrtf(tot * (1.0f / (float)Cq) + 1e-6f);
    float4 wv = *(const float4*)(w + tid * 4);
    float o[4] = { v.x*wv.x*scale, v.y*wv.y*scale, v.z*wv.z*scale, v.w*wv.w*scale };
    ushort4 oh, ol;
    u16* ph = (u16*)&oh; u16* pl = (u16*)&ol;
    #pragma unroll
    for (int i = 0; i < 4; i++) {
        f16 hi = (f16)o[i]; f16 lo = (f16)(o[i] - (float)hi);
        ph[i] = f16bits(hi); pl[i] = f16bits(lo);
    }
    *(ushort4*)(hh + (size_t)row * Cq + tid * 4) = oh;
    *(ushort4*)(hl + (size_t)row * Cq + tid * 4) = ol;
}

// ---------------------------------------------------------------------------
// RMSNorm -> fp32 + bf16 (FFN branch: fp32 feeds router, bf16 feeds MoE)
// ---------------------------------------------------------------------------
__global__ __launch_bounds__(256) void rmsnorm2_k(const float* __restrict__ x,
                                                  const float* __restrict__ w,
                                                  float* __restrict__ hn,
                                                  u16* __restrict__ hnb) {
    int row = blockIdx.x;
    int tid = threadIdx.x;
    const float* xr = x + (size_t)row * Cq;
    float4 v = *(const float4*)(xr + tid * 4);
    float ss = v.x*v.x + v.y*v.y + v.z*v.z + v.w*v.w;
    #pragma unroll
    for (int off = 32; off; off >>= 1) ss += __shfl_xor(ss, off);
    __shared__ float red[4];
    if ((tid & 63) == 0) red[tid >> 6] = ss;
    __syncthreads();
    float tot = red[0] + red[1] + red[2] + red[3];
    float scale = rsqrtf(tot * (1.0f / (float)Cq) + 1e-6f);
    float4 wv = *(const float4*)(w + tid * 4);
    float4 o = make_float4(v.x*wv.x*scale, v.y*wv.y*scale, v.z*wv.z*scale, v.w*wv.w*scale);
    *(float4*)(hn + (size_t)row * Cq + tid * 4) = o;
    ushort4 ob = make_ushort4(f2bf(o.x), f2bf(o.y), f2bf(o.z), f2bf(o.w));
    *(ushort4*)(hnb + (size_t)row * Cq + tid * 4) = ob;
}

// ---------------------------------------------------------------------------
// Split-f16 MFMA GEMM for QKV / O-proj: C[4096,1024] = A @ W^T (+x residual)
// A pre-split (hi/lo u16 planes); W fp32, split in-kernel during staging.
// 128x128 tile, BK=32, 3-term MFMA (ah*bh + ah*bl + al*bh) ~ fp32 precision.
// ---------------------------------------------------------------------------
__global__ __launch_bounds__(256, 2) void gemm_qkv(const u16* __restrict__ Ahg,
                                                   const u16* __restrict__ Alg,
                                                   const float* __restrict__ W,
                                                   float* __restrict__ C,
                                                   const float* __restrict__ aux,
                                                   int mode) {
    __shared__ u16 Ah[128*32], Al[128*32], Bh[128*32], Bl[128*32];
    int tid = threadIdx.x;
    int wave = tid >> 6, lane = tid & 63;
    int wm = wave >> 1, wn = wave & 1;
    int bx = blockIdx.x, by = blockIdx.y;
    int srow = tid >> 2, sch = (tid & 3) * 8;

    const u16* A0 = Ahg + (size_t)(by*128 + srow) * Cq + sch;
    const u16* A1 = A0 + (size_t)64 * Cq;
    const u16* L0 = Alg + (size_t)(by*128 + srow) * Cq + sch;
    const u16* L1 = L0 + (size_t)64 * Cq;
    const float* W0 = W + (size_t)(bx*128 + srow) * Cq + sch;
    const float* W1 = W0 + (size_t)64 * Cq;
    int lo0 = srow*32 + sch, lo1 = (srow+64)*32 + sch;

    f32x4v acc[4][4];
    #pragma unroll
    for (int i = 0; i < 4; i++)
        #pragma unroll
        for (int j = 0; j < 4; j++)
            #pragma unroll
            for (int r = 0; r < 4; r++) acc[i][j][r] = 0.0f;

    for (int k0 = 0; k0 < Cq; k0 += 32) {
        stage16(A0 + k0, Ah + lo0);
        stage16(A1 + k0, Ah + lo1);
        stage16(L0 + k0, Al + lo0);
        stage16(L1 + k0, Al + lo1);
        // B: load fp32, split hi/lo in-register
        float wr0[8], wr1[8];
        *(float4*)&wr0[0] = *(const float4*)(W0 + k0);
        *(float4*)&wr0[4] = *(const float4*)(W0 + k0 + 4);
        *(float4*)&wr1[0] = *(const float4*)(W1 + k0);
        *(float4*)&wr1[4] = *(const float4*)(W1 + k0 + 4);
        f16x8 bh0, bl0, bh1, bl1;
        #pragma unroll
        for (int i = 0; i < 8; i++) {
            f16 h0 = (f16)wr0[i]; bh0[i] = h0; bl0[i] = (f16)(wr0[i] - (float)h0);
            f16 h1 = (f16)wr1[i]; bh1[i] = h1; bl1[i] = (f16)(wr1[i] - (float)h1);
        }
        *(f16x8*)(void*)(Bh + lo0) = bh0;
        *(f16x8*)(void*)(Bl + lo0) = bl0;
        *(f16x8*)(void*)(Bh + lo1) = bh1;
        *(f16x8*)(void*)(Bl + lo1) = bl1;
        __syncthreads();

        int fr = lane & 15, fk = (lane >> 4) * 8;
        f16x8 ah[4], al[4], bhf[4], blf[4];
        #pragma unroll
        for (int mi = 0; mi < 4; mi++) {
            ah[mi] = *(const f16x8*)(const void*)&Ah[(wm*64 + mi*16 + fr)*32 + fk];
            al[mi] = *(const f16x8*)(const void*)&Al[(wm*64 + mi*16 + fr)*32 + fk];
        }
        #pragma unroll
        for (int ni = 0; ni < 4; ni++) {
            bhf[ni] = *(const f16x8*)(const void*)&Bh[(wn*64 + ni*16 + fr)*32 + fk];
            blf[ni] = *(const f16x8*)(const void*)&Bl[(wn*64 + ni*16 + fr)*32 + fk];
        }
        #pragma unroll
        for (int mi = 0; mi < 4; mi++)
            #pragma unroll
            for (int ni = 0; ni < 4; ni++) {
                acc[mi][ni] = __builtin_amdgcn_mfma_f32_16x16x32_f16(ah[mi], bhf[ni], acc[mi][ni], 0, 0, 0);
                acc[mi][ni] = __builtin_amdgcn_mfma_f32_16x16x32_f16(ah[mi], blf[ni], acc[mi][ni], 0, 0, 0);
                acc[mi][ni] = __builtin_amdgcn_mfma_f32_16x16x32_f16(al[mi], bhf[ni], acc[mi][ni], 0, 0, 0);
            }
        __syncthreads();
    }

    int cr = (lane >> 4) * 4, cc = lane & 15;
    #pragma unroll
    for (int mi = 0; mi < 4; mi++)
        #pragma unroll
        for (int ni = 0; ni < 4; ni++)
            #pragma unroll
            for (int r = 0; r < 4; r++) {
                int row = by*128 + wm*64 + mi*16 + cr + r;
                int col = bx*128 + wn*64 + ni*16 + cc;
                size_t off = (size_t)row * Cq + col;
                float vout = acc[mi][ni][r];
                if (mode) vout += aux[off];
                C[off] = vout;
            }
}

// ---------------------------------------------------------------------------
// RoPE + split-fp16 (q scaled by 0.125)
// ---------------------------------------------------------------------------
__global__ __launch_bounds__(256) void ropesplit_k(const float* __restrict__ src,
                                                   u16* __restrict__ hh,
                                                   u16* __restrict__ hl,
                                                   const float* __restrict__ cosb,
                                                   const float* __restrict__ sinb,
                                                   float scale) {
    int row = blockIdx.x;
    int tid = threadIdx.x;
    int t = row & (Tq - 1);
    #pragma unroll
    for (int pi = 0; pi < 2; pi++) {
        int p = tid * 2 + pi;
        int h = p >> 5, d = p & 31;
        size_t i0 = (size_t)row * Cq + h * Dq + d;
        float a = src[i0], b = src[i0 + 32];
        float c0 = cosb[t * Dq + d],      s0 = sinb[t * Dq + d];
        float c1 = cosb[t * Dq + d + 32], s1 = sinb[t * Dq + d + 32];
        float o0 = (a * c0 - b * s0) * scale;
        float o1 = (b * c1 + a * s1) * scale;
        f16 h0 = (f16)o0; f16 l0 = (f16)(o0 - (float)h0);
        f16 h1 = (f16)o1; f16 l1 = (f16)(o1 - (float)h1);
        hh[i0]      = f16bits(h0);
        hl[i0]      = f16bits(l0);
        hh[i0 + 32] = f16bits(h1);
        hl[i0 + 32] = f16bits(l1);
    }
}

// ---------------------------------------------------------------------------
// V transpose + split: v fp32 [b][t][h*64+d] -> vth/vtl u16 [bh][d][t]
// ---------------------------------------------------------------------------
__global__ __launch_bounds__(256) void vtrans_k(const float* __restrict__ v,
                                                u16* __restrict__ vth,
                                                u16* __restrict__ vtl) {
    __shared__ u16 Th[64 * 72];
    __shared__ u16 Tl[64 * 72];
    int tc = blockIdx.x;
    int bh = blockIdx.y;
    int b = bh >> 4, h = bh & 15;
    int tid = threadIdx.x;
    int tr = tid >> 2;
    int dc = (tid & 3) * 16;
    size_t gin = ((size_t)(b * Tq + tc * 64 + tr)) * Cq + h * Dq + dc;
    #pragma unroll
    for (int i = 0; i < 16; i += 4) {
        float4 f = *(const float4*)(v + gin + i);
        float fv[4] = {f.x, f.y, f.z, f.w};
        #pragma unroll
        for (int j = 0; j < 4; j++) {
            f16 hi = (f16)fv[j];
            f16 lo = (f16)(fv[j] - (float)hi);
            Th[(dc + i + j) * 72 + tr] = f16bits(hi);
            Tl[(dc + i + j) * 72 + tr] = f16bits(lo);
        }
    }
    __syncthreads();
    int dr = tid >> 2;
    int cc = (tid & 3) * 16;
    size_t gout = ((size_t)(bh * 64 + dr)) * Tq + tc * 64 + cc;
    *(uint4*)(vth + gout)     = *(uint4*)(Th + dr * 72 + cc);
    *(uint4*)(vth + gout + 8) = *(uint4*)(Th + dr * 72 + cc + 8);
    *(uint4*)(vtl + gout)     = *(uint4*)(Tl + dr * 72 + cc);
    *(uint4*)(vtl + gout + 8) = *(uint4*)(Tl + dr * 72 + cc + 8);
}

// ---------------------------------------------------------------------------
// Flash attention, split-fp16 MFMA, TRIANGLE-PAIRED: block j processes
// q-tiles (31-j) then (j) -> uniform 33 tile-units/block, 512 blocks = 2/CU.
// ---------------------------------------------------------------------------
#define AST 72
__global__ __launch_bounds__(256, 2) void attn_f16(const u16* __restrict__ qh_g,
                                                   const u16* __restrict__ ql_g,
                                                   const u16* __restrict__ kh_g,
                                                   const u16* __restrict__ kl_g,
                                                   const u16* __restrict__ vth_g,
                                                   const u16* __restrict__ vtl_g,
                                                   u16* __restrict__ yh_g,
                                                   u16* __restrict__ yl_g) {
    __shared__ u16 Qh[64*AST], Ql[64*AST];
    __shared__ u16 Kh[64*AST], Kl[64*AST];
    __shared__ u16 Vh[64*AST], Vl[64*AST];
    __shared__ u16 Ph[64*AST], Pl[64*AST];

    int j  = blockIdx.x;           // 0..15
    int bh = blockIdx.y;
    int b = bh >> 4, h = bh & 15;
    int tid = threadIdx.x;
    int wv = tid >> 6, lane = tid & 63;
    int fr = lane & 15, fg = lane >> 4;
    int sr = tid >> 2, sc = (tid & 3) * 16;
    int aoff = (wv * 16 + fr) * AST + fg * 8;

    #pragma unroll
    for (int pass = 0; pass < 2; pass++) {
        int qt = pass == 0 ? (31 - j) : j;

        __syncthreads();   // all waves done with prior pass's LDS reads
        {
            size_t g = ((size_t)(b * Tq + qt * 64 + sr)) * Cq + h * Dq + sc;
            *(uint4*)(Qh + sr*AST + sc)     = *(const uint4*)(qh_g + g);
            *(uint4*)(Qh + sr*AST + sc + 8) = *(const uint4*)(qh_g + g + 8);
            *(uint4*)(Ql + sr*AST + sc)     = *(const uint4*)(ql_g + g);
            *(uint4*)(Ql + sr*AST + sc + 8) = *(const uint4*)(ql_g + g + 8);
        }

        f32x4v acc_o[4];
        float m_i[4], l_i[4];
        #pragma unroll
        for (int i = 0; i < 4; i++) {
            m_i[i] = -1e30f; l_i[i] = 0.0f;
            #pragma unroll
            for (int r = 0; r < 4; r++) acc_o[i][r] = 0.0f;
        }

        for (int kt = 0; kt <= qt; kt++) {
            __syncthreads();
            {
                size_t kg = ((size_t)(b * Tq + kt * 64 + sr)) * Cq + h * Dq + sc;
                size_t vg = ((size_t)(bh * 64 + sr)) * Tq + kt * 64 + sc;
                *(uint4*)(Kh + sr*AST + sc)     = *(const uint4*)(kh_g + kg);
                *(uint4*)(Kh + sr*AST + sc + 8) = *(const uint4*)(kh_g + kg + 8);
                *(uint4*)(Kl + sr*AST + sc)     = *(const uint4*)(kl_g + kg);
                *(uint4*)(Kl + sr*AST + sc + 8) = *(const uint4*)(kl_g + kg + 8);
                *(uint4*)(Vh + sr*AST + sc)     = *(const uint4*)(vth_g + vg);
                *(uint4*)(Vh + sr*AST + sc + 8) = *(const uint4*)(vth_g + vg + 8);
                *(uint4*)(Vl + sr*AST + sc)     = *(const uint4*)(vtl_g + vg);
                *(uint4*)(Vl + sr*AST + sc + 8) = *(const uint4*)(vtl_g + vg + 8);
            }
            __syncthreads();

            // S = Q K^T (3-term split)
            f16x8 aqh0 = *(const f16x8*)(const void*)(Qh + aoff);
            f16x8 aqh1 = *(const f16x8*)(const void*)(Qh + aoff + 32);
            f16x8 aql0 = *(const f16x8*)(const void*)(Ql + aoff);
            f16x8 aql1 = *(const f16x8*)(const void*)(Ql + aoff + 32);

            f32x4v s[4];
            #pragma unroll
            for (int ni = 0; ni < 4; ni++) {
                int boff = (ni * 16 + fr) * AST + fg * 8;
                f16x8 kh0 = *(const f16x8*)(const void*)(Kh + boff);
                f16x8 kh1 = *(const f16x8*)(const void*)(Kh + boff + 32);
                f16x8 kl0 = *(const f16x8*)(const void*)(Kl + boff);
                f16x8 kl1 = *(const f16x8*)(const void*)(Kl + boff + 32);
                f32x4v t;
                #pragma unroll
                for (int r = 0; r < 4; r++) t[r] = 0.0f;
                t = __builtin_amdgcn_mfma_f32_16x16x32_f16(aqh0, kh0, t, 0, 0, 0);
                t = __builtin_amdgcn_mfma_f32_16x16x32_f16(aqh1, kh1, t, 0, 0, 0);
                t = __builtin_amdgcn_mfma_f32_16x16x32_f16(aqh0, kl0, t, 0, 0, 0);
                t = __builtin_amdgcn_mfma_f32_16x16x32_f16(aqh1, kl1, t, 0, 0, 0);
                t = __builtin_amdgcn_mfma_f32_16x16x32_f16(aql0, kh0, t, 0, 0, 0);
                t = __builtin_amdgcn_mfma_f32_16x16x32_f16(aql1, kh1, t, 0, 0, 0);
                s[ni] = t;
            }

            if (kt == qt) {
                #pragma unroll
                for (int ni = 0; ni < 4; ni++) {
                    int col = ni * 16 + fr;
                    #pragma unroll
                    for (int r = 0; r < 4; r++) {
                        int row = wv * 16 + fg * 4 + r;
                        if (col > row) s[ni][r] = -1e30f;
                    }
                }
            }

            // online softmax
            float p[4][4];
            #pragma unroll
            for (int r = 0; r < 4; r++) {
                float mx = fmaxf(fmaxf(s[0][r], s[1][r]), fmaxf(s[2][r], s[3][r]));
                #pragma unroll
                for (int off = 1; off < 16; off <<= 1)
                    mx = fmaxf(mx, __shfl_xor(mx, off, 16));
                float mn = fmaxf(m_i[r], mx);
                float rs = 0.0f;
                #pragma unroll
                for (int ni = 0; ni < 4; ni++) {
                    p[ni][r] = __expf(s[ni][r] - mn);
                    rs += p[ni][r];
                }
                #pragma unroll
                for (int off = 1; off < 16; off <<= 1)
                    rs += __shfl_xor(rs, off, 16);
                float alpha = __expf(m_i[r] - mn);
                l_i[r] = l_i[r] * alpha + rs;
                m_i[r] = mn;
                #pragma unroll
                for (int ni = 0; ni < 4; ni++) acc_o[ni][r] *= alpha;
            }

            // write P (split); rows are wave-private, no barrier needed
            #pragma unroll
            for (int ni = 0; ni < 4; ni++) {
                #pragma unroll
                for (int r = 0; r < 4; r++) {
                    int off = (wv * 16 + fg * 4 + r) * AST + ni * 16 + fr;
                    f16 ph = (f16)p[ni][r];
                    f16 pl = (f16)(p[ni][r] - (float)ph);
                    Ph[off] = f16bits(ph);
                    Pl[off] = f16bits(pl);
                }
            }

            // O += P V (3-term split)
            f16x8 aph0 = *(const f16x8*)(const void*)(Ph + aoff);
            f16x8 aph1 = *(const f16x8*)(const void*)(Ph + aoff + 32);
            f16x8 apl0 = *(const f16x8*)(const void*)(Pl + aoff);
            f16x8 apl1 = *(const f16x8*)(const void*)(Pl + aoff + 32);
            #pragma unroll
            for (int ni = 0; ni < 4; ni++) {
                int boff = (ni * 16 + fr) * AST + fg * 8;
                f16x8 vh0 = *(const f16x8*)(const void*)(Vh + boff);
                f16x8 vh1 = *(const f16x8*)(const void*)(Vh + boff + 32);
                f16x8 vl0 = *(const f16x8*)(const void*)(Vl + boff);
                f16x8 vl1 = *(const f16x8*)(const void*)(Vl + boff + 32);
                f32x4v t = acc_o[ni];
                t = __builtin_amdgcn_mfma_f32_16x16x32_f16(aph0, vh0, t, 0, 0, 0);
                t = __builtin_amdgcn_mfma_f32_16x16x32_f16(aph1, vh1, t, 0, 0, 0);
                t = __builtin_amdgcn_mfma_f32_16x16x32_f16(aph0, vl0, t, 0, 0, 0);
                t = __builtin_amdgcn_mfma_f32_16x16x32_f16(aph1, vl1, t, 0, 0, 0);
                t = __builtin_amdgcn_mfma_f32_16x16x32_f16(apl0, vh0, t, 0, 0, 0);
                t = __builtin_amdgcn_mfma_f32_16x16x32_f16(apl1, vh1, t, 0, 0, 0);
                acc_o[ni] = t;
            }
        }

        // epilogue: split y write
        #pragma unroll
        for (int r = 0; r < 4; r++) {
            float inv = 1.0f / l_i[r];
            int row = qt * 64 + wv * 16 + fg * 4 + r;
            size_t base = ((size_t)(b * Tq + row)) * Cq + h * Dq + fr;
            #pragma unroll
            for (int ni = 0; ni < 4; ni++) {
                float yv = acc_o[ni][r] * inv;
                f16 hi = (f16)yv;
                f16 lo = (f16)(yv - (float)hi);
                yh_g[base + ni * 16] = f16bits(hi);
                yl_g[base + ni * 16] = f16bits(lo);
            }
        }
    }
}

// ---------------------------------------------------------------------------
// Zero the expert counters (ws is poisoned before every call)
// ---------------------------------------------------------------------------
__global__ void zero_k(int* cnt) {
    if (threadIdx.x < Eq) cnt[threadIdx.x] = 0;
}

// ---------------------------------------------------------------------------
// Router: fp32 logits, top-2; emit per-expert (token, gate) lists via atomics.
// ---------------------------------------------------------------------------
__global__ __launch_bounds__(64) void router_k(const float* __restrict__ hn,
                                               const float* __restrict__ rw,
                                               int* __restrict__ cnt,
                                               int* __restrict__ idxl,
                                               float* __restrict__ gvl) {
    int tkn = blockIdx.x;
    int lane = threadIdx.x;
    float acc[Eq] = {};
    for (int it = 0; it < Cq / 64; it++) {
        float hv = hn[(size_t)tkn * Cq + it * 64 + lane];
        #pragma unroll
        for (int e = 0; e < Eq; e++)
            acc[e] = fmaf(hv, rw[e * Cq + it * 64 + lane], acc[e]);
    }
    #pragma unroll
    for (int e = 0; e < Eq; e++) {
        #pragma unroll
        for (int off = 32; off; off >>= 1) acc[e] += __shfl_xor(acc[e], off);
    }
    int i0 = 0;
    #pragma unroll
    for (int e = 1; e < Eq; e++) if (acc[e] > acc[i0]) i0 = e;
    int i1 = (i0 == 0) ? 1 : 0;
    #pragma unroll
    for (int e = 0; e < Eq; e++)
        if (e != i0 && acc[e] > acc[i1]) i1 = e;
    float p1 = __expf(acc[i1] - acc[i0]);
    float g0 = 1.0f / (1.0f + p1);
    float g1 = p1 / (1.0f + p1);
    if (lane == 0) {
        int p0 = atomicAdd(&cnt[i0], 1);
        idxl[i0 * NTOK + p0] = tkn;
        gvl[i0 * NTOK + p0] = g0;
        int p1i = atomicAdd(&cnt[i1], 1);
        idxl[i1 * NTOK + p1i] = tkn;
        gvl[i1 * NTOK + p1i] = g1;
    }
}

// ---------------------------------------------------------------------------
// Setup: 128-padded segment offsets + tile->expert table (<= 72 tiles).
// ---------------------------------------------------------------------------
__global__ void setup_k(const int* __restrict__ cnt, int* __restrict__ seg,
                        int* __restrict__ texp, int* __restrict__ ttot) {
    if (threadIdx.x == 0) {
        int base = 0;
        for (int e = 0; e < Eq; e++) {
            seg[e] = base * 128;
            int t = (cnt[e] + 127) >> 7;
            for (int i = 0; i < t; i++) texp[base + i] = e;
            base += t;
        }
        *ttot = base;
    }
}

// ---------------------------------------------------------------------------
// MoE up-proj over gathered tokens: gbuf = bf16(silu(A@w1^T) * (A@w3^T)).
// A rows gathered in-staging via per-lane global addresses (hnb[token]).
// B (w1/w3) fp32 -> bf16 in-register during staging. Grid (12, 72).
// ---------------------------------------------------------------------------
__global__ __launch_bounds__(256, 2) void moe_w13(const u16* __restrict__ hnb,
                                                  const float* __restrict__ w1,
                                                  const float* __restrict__ w3,
                                                  u16* __restrict__ gbuf,
                                                  const int* __restrict__ cnt,
                                                  const int* __restrict__ seg,
                                                  const int* __restrict__ texp,
                                                  const int* __restrict__ ttot,
                                                  const int* __restrict__ idxl) {
    int by = blockIdx.y;
    if (by >= *ttot) return;
    int e = texp[by];
    const float* w1e = w1 + (size_t)e * HDq * Cq;
    const float* w3e = w3 + (size_t)e * HDq * Cq;
    int cnte = cnt[e], sege = seg[e];
    const int* idxe = idxl + e * NTOK;

    __shared__ u16 As[128*32], B1[128*32], B3[128*32];
    int tid = threadIdx.x;
    int wave = tid >> 6, lane = tid & 63;
    int wm = wave >> 1, wn = wave & 1;
    int bx = blockIdx.x;
    int srow = tid >> 2, sch = (tid & 3) * 8;

    int r0 = by*128 + srow, r1 = r0 + 64;
    int li0 = r0 - sege, li1 = r1 - sege;
    int tok0 = idxe[li0 < cnte ? li0 : 0];
    int tok1 = idxe[li1 < cnte ? li1 : 0];
    const u16* A0 = hnb + (size_t)tok0 * Cq + sch;
    const u16* A1 = hnb + (size_t)tok1 * Cq + sch;
    const float* W10 = w1e + (size_t)(bx*128 + srow) * Cq + sch;
    const float* W11 = W10 + (size_t)64 * Cq;
    const float* W30 = w3e + (size_t)(bx*128 + srow) * Cq + sch;
    const float* W31 = W30 + (size_t)64 * Cq;
    int lo0 = srow*32 + sch, lo1 = (srow+64)*32 + sch;

    f32x4v acc1[4][4], acc3[4][4];
    #pragma unroll
    for (int i = 0; i < 4; i++)
        #pragma unroll
        for (int j = 0; j < 4; j++)
            #pragma unroll
            for (int r = 0; r < 4; r++) { acc1[i][j][r] = 0.0f; acc3[i][j][r] = 0.0f; }

    for (int k0 = 0; k0 < Cq; k0 += 32) {
        stage16(A0 + k0, As + lo0);
        stage16(A1 + k0, As + lo1);
        float x1a[8], x1b[8], x3a[8], x3b[8];
        *(float4*)&x1a[0] = *(const float4*)(W10 + k0);
        *(float4*)&x1a[4] = *(const float4*)(W10 + k0 + 4);
        *(float4*)&x1b[0] = *(const float4*)(W11 + k0);
        *(float4*)&x1b[4] = *(const float4*)(W11 + k0 + 4);
        *(float4*)&x3a[0] = *(const float4*)(W30 + k0);
        *(float4*)&x3a[4] = *(const float4*)(W30 + k0 + 4);
        *(float4*)&x3b[0] = *(const float4*)(W31 + k0);
        *(float4*)&x3b[4] = *(const float4*)(W31 + k0 + 4);
        ushort4 p0[2], p1[2], p2[2], p3[2];
        u16* q0 = (u16*)p0; u16* q1 = (u16*)p1; u16* q2 = (u16*)p2; u16* q3 = (u16*)p3;
        #pragma unroll
        for (int i = 0; i < 8; i++) {
            q0[i] = f2bf(x1a[i]); q1[i] = f2bf(x1b[i]);
            q2[i] = f2bf(x3a[i]); q3[i] = f2bf(x3b[i]);
        }
        *(uint4*)(B1 + lo0) = *(uint4*)p0;
        *(uint4*)(B1 + lo1) = *(uint4*)p1;
        *(uint4*)(B3 + lo0) = *(uint4*)p2;
        *(uint4*)(B3 + lo1) = *(uint4*)p3;
        __syncthreads();

        int fr = lane & 15, fk = (lane >> 4) * 8;
        bf16x8 af[4], b1f[4], b3f[4];
        #pragma unroll
        for (int mi = 0; mi < 4; mi++)
            af[mi] = *(const bf16x8*)&As[(wm*64 + mi*16 + fr) * 32 + fk];
        #pragma unroll
        for (int ni = 0; ni < 4; ni++) {
            b1f[ni] = *(const bf16x8*)&B1[(wn*64 + ni*16 + fr) * 32 + fk];
            b3f[ni] = *(const bf16x8*)&B3[(wn*64 + ni*16 + fr) * 32 + fk];
        }
        #pragma unroll
        for (int mi = 0; mi < 4; mi++)
            #pragma unroll
            for (int ni = 0; ni < 4; ni++) {
                acc1[mi][ni] = __builtin_amdgcn_mfma_f32_16x16x32_bf16(af[mi], b1f[ni], acc1[mi][ni], 0, 0, 0);
                acc3[mi][ni] = __builtin_amdgcn_mfma_f32_16x16x32_bf16(af[mi], b3f[ni], acc3[mi][ni], 0, 0, 0);
            }
        __syncthreads();
    }

    int cr = (lane >> 4) * 4, cc = lane & 15;
    #pragma unroll
    for (int mi = 0; mi < 4; mi++)
        #pragma unroll
        for (int ni = 0; ni < 4; ni++)
            #pragma unroll
            for (int r = 0; r < 4; r++) {
                int row = by*128 + wm*64 + mi*16 + cr + r;
                int col = bx*128 + wn*64 + ni*16 + cc;
                gbuf[(size_t)row * HDq + col] = f2bf(silu_f(acc1[mi][ni][r]) * acc3[mi][ni][r]);
            }
}

// ---------------------------------------------------------------------------
// MoE down-proj: out[token] += gate * (gbuf @ w2^T), atomic scatter-add.
// Grid (8, 72). K = 1536.
// ---------------------------------------------------------------------------
__global__ __launch_bounds__(256, 2) void moe_w2(const u16* __restrict__ gbuf,
                                                 const float* __restrict__ w2,
                                                 float* __restrict__ out,
                                                 const int* __restrict__ cnt,
                                                 const int* __restrict__ seg,
                                                 const int* __restrict__ texp,
                                                 const int* __restrict__ ttot,
                                                 const int* __restrict__ idxl,
                                                 const float* __restrict__ gvl) {
    int by = blockIdx.y;
    if (by >= *ttot) return;
    int e = texp[by];
    const float* w2e = w2 + (size_t)e * Cq * HDq;
    int cnte = cnt[e], sege = seg[e];
    const int* idxe = idxl + e * NTOK;
    const float* gve = gvl + e * NTOK;

    __shared__ u16 As[128*32], Bs[128*32];
    int tid = threadIdx.x;
    int wave = tid >> 6, lane = tid & 63;
    int wm = wave >> 1, wn = wave & 1;
    int bx = blockIdx.x;
    int srow = tid >> 2, sch = (tid & 3) * 8;

    const u16* A0 = gbuf + (size_t)(by*128 + srow) * HDq + sch;
    const u16* A1 = A0 + (size_t)64 * HDq;
    const float* W0 = w2e + (size_t)(bx*128 + srow) * HDq + sch;
    const float* W1 = W0 + (size_t)64 * HDq;
    int lo0 = srow*32 + sch, lo1 = (srow+64)*32 + sch;

    f32x4v acc[4][4];
    #pragma unroll
    for (int i = 0; i < 4; i++)
        #pragma unroll
        for (int j = 0; j < 4; j++)
            #pragma unroll
            for (int r = 0; r < 4; r++) acc[i][j][r] = 0.0f;

    for (int k0 = 0; k0 < HDq; k0 += 32) {
        stage16(A0 + k0, As + lo0);
        stage16(A1 + k0, As + lo1);
        float xa[8], xb[8];
        *(float4*)&xa[0] = *(const float4*)(W0 + k0);
        *(float4*)&xa[4] = *(const float4*)(W0 + k0 + 4);
        *(float4*)&xb[0] = *(const float4*)(W1 + k0);
        *(float4*)&xb[4] = *(const float4*)(W1 + k0 + 4);
        ushort4 pa[2], pb[2];
        u16* qa = (u16*)pa; u16* qb_ = (u16*)pb;
        #pragma unroll
        for (int i = 0; i < 8; i++) { qa[i] = f2bf(xa[i]); qb_[i] = f2bf(xb[i]); }
        *(uint4*)(Bs + lo0) = *(uint4*)pa;
        *(uint4*)(Bs + lo1) = *(uint4*)pb;
        __syncthreads();

        int fr = lane & 15, fk = (lane >> 4) * 8;
        bf16x8 af[4], bf_[4];
        #pragma unroll
        for (int mi = 0; mi < 4; mi++)
            af[mi] = *(const bf16x8*)&As[(wm*64 + mi*16 + fr) * 32 + fk];
        #pragma unroll
        for (int ni = 0; ni < 4; ni++)
            bf_[ni] = *(const bf16x8*)&Bs[(wn*64 + ni*16 + fr) * 32 + fk];
        #pragma unroll
        for (int mi = 0; mi < 4; mi++)
            #pragma unroll
            for (int ni = 0; ni < 4; ni++)
                acc[mi][ni] = __builtin_amdgcn_mfma_f32_16x16x32_bf16(af[mi], bf_[ni], acc[mi][ni], 0, 0, 0);
        __syncthreads();
    }

    int cr = (lane >> 4) * 4, cc = lane & 15;
    #pragma unroll
    for (int mi = 0; mi < 4; mi++)
        #pragma unroll
        for (int r = 0; r < 4; r++) {
            int row = by*128 + wm*64 + mi*16 + cr + r;
            int local = row - sege;
            if (local < cnte) {
                int token = idxe[local];
                float g = gve[local];
                #pragma unroll
                for (int ni = 0; ni < 4; ni++) {
                    int col = bx*128 + wn*64 + ni*16 + cc;
                    atomicAdd(&out[(size_t)token * Cq + col], g * acc[mi][ni][r]);
                }
            }
        }
}

// ---------------------------------------------------------------------------
// Launch
// ---------------------------------------------------------------------------
extern "C" void kernel_launch(void* const* d_in, const int* in_sizes, int n_in,
                              void* d_out, int out_size, void* d_ws, size_t ws_size,
                              hipStream_t stream) {
    (void)in_sizes; (void)n_in; (void)out_size; (void)ws_size;

    const float* x     = (const float*)d_in[0];
    const float* ropec = (const float*)d_in[1];
    const float* ropes = (const float*)d_in[2];
    const float* anw   = (const float*)d_in[3];
    const float* q_w   = (const float*)d_in[4];
    const float* k_w   = (const float*)d_in[5];
    const float* v_w   = (const float*)d_in[6];
    const float* o_w   = (const float*)d_in[7];
    const float* fnw   = (const float*)d_in[8];
    const float* rtw   = (const float*)d_in[9];
    const float* w1    = (const float*)d_in[10];
    const float* w2    = (const float*)d_in[11];
    const float* w3    = (const float*)d_in[12];
    float* out = (float*)d_out;

    // workspace map (MiB offsets; peak 52 MiB, phases 1-2 peak 64 MiB):
    //  P1: hh@0 hl@8 | q@16 k@32 v@48  (fp32 16 MiB each)
    //  P2: vth@0 vtl@8 | kh@16 kl@24 | yh@32 yl@40 | qh@48 ql@56
    //  P3: hn@0 | hnb@16 | meta@24 | gbuf@25..52
    float* ws = (float*)d_ws;
    u16* hh = (u16*)(ws + MB(0));
    u16* hl = (u16*)(ws + MB(8));
    float* qf = ws + MB(16);
    float* kf = ws + MB(32);
    float* vf = ws + MB(48);
    u16* vth = (u16*)(ws + MB(0));
    u16* vtl = (u16*)(ws + MB(8));
    u16* kh  = (u16*)(ws + MB(16));
    u16* kl  = (u16*)(ws + MB(24));
    u16* yh  = (u16*)(ws + MB(32));
    u16* yl  = (u16*)(ws + MB(40));
    u16* qh  = (u16*)(ws + MB(48));
    u16* ql  = (u16*)(ws + MB(56));
    float* hn  = ws + MB(0);
    u16* hnb   = (u16*)(ws + MB(16));
    int* cntp  = (int*)(ws + MB(24));
    int* segp  = cntp + 8;
    int* texp  = cntp + 16;    // 72 entries
    int* ttot  = cntp + 96;
    int* idxl  = cntp + 256;                  // 8*4096 ints
    float* gvl = (float*)(cntp + 256 + Eq*NTOK);
    u16* gbuf  = (u16*)(ws + MB(25));         // 9216 x 1536 bf16 = 27 MiB

    const int M = NTOK;

    // 1. attn rmsnorm -> split hi/lo
    hipLaunchKernelGGL(rmsnorm_split_k, dim3(M), dim3(256), 0, stream, x, anw, hh, hl);

    // 2-4. Q,K,V projections (split-f16 MFMA, ~fp32 precision)
    hipLaunchKernelGGL(gemm_qkv, dim3(Cq/128, M/128), dim3(256), 0, stream,
                       hh, hl, q_w, qf, (const float*)nullptr, 0);
    hipLaunchKernelGGL(gemm_qkv, dim3(Cq/128, M/128), dim3(256), 0, stream,
                       hh, hl, k_w, kf, (const float*)nullptr, 0);
    hipLaunchKernelGGL(gemm_qkv, dim3(Cq/128, M/128), dim3(256), 0, stream,
                       hh, hl, v_w, vf, (const float*)nullptr, 0);

    // 5. V transpose+split (over hh/hl), then RoPE+split q (over v), k (over q)
    hipLaunchKernelGGL(vtrans_k, dim3(32, 32), dim3(256), 0, stream, vf, vth, vtl);
    hipLaunchKernelGGL(ropesplit_k, dim3(M), dim3(256), 0, stream,
                       qf, qh, ql, ropec, ropes, 0.125f);
    hipLaunchKernelGGL(ropesplit_k, dim3(M), dim3(256), 0, stream,
                       kf, kh, kl, ropec, ropes, 1.0f);

    // 6. flash attention (triangle-paired) -> yh/yl
    hipLaunchKernelGGL(attn_f16, dim3(16, Bq*Hq), dim3(256), 0, stream,
                       qh, ql, kh, kl, vth, vtl, yh, yl);

    // 7. O projection + residual -> out
    hipLaunchKernelGGL(gemm_qkv, dim3(Cq/128, M/128), dim3(256), 0, stream,
                       yh, yl, o_w, out, x, 1);

    // 8. ffn rmsnorm -> hn fp32 + hnb bf16
    hipLaunchKernelGGL(rmsnorm2_k, dim3(M), dim3(256), 0, stream, out, fnw, hn, hnb);

    // 9. router (fp32) -> per-expert lists; then tile table
    hipLaunchKernelGGL(zero_k, dim3(1), dim3(64), 0, stream, cntp);
    hipLaunchKernelGGL(router_k, dim3(M), dim3(64), 0, stream, hn, rtw, cntp, idxl, gvl);
    hipLaunchKernelGGL(setup_k, dim3(1), dim3(64), 0, stream, cntp, segp, texp, ttot);

    // 10. MoE over gathered tokens (single launch each)
    hipLaunchKernelGGL(moe_w13, dim3(HDq/128, 72), dim3(256), 0, stream,
                       hnb, w1, w3, gbuf, cntp, segp, texp, ttot, idxl);
    hipLaunchKernelGGL(moe_w2, dim3(Cq/128, 72), dim3(256), 0, stream,
                       gbuf, w2, out, cntp, segp, texp, ttot, idxl, gvl);
}

// Round 5
// 753.959 us; speedup vs baseline: 13.9249x; 1.2269x over previous
//
#include <hip/hip_runtime.h>
#include <hip/hip_bf16.h>
#include <math.h>

// Problem constants
#define Bq 2
#define Tq 2048
#define Cq 1024
#define Hq 16
#define Dq 64
#define Eq 8
#define HDq 1536
#define NTOK (Bq*Tq)        // 4096 tokens

typedef unsigned short u16;
typedef _Float16 f16;
typedef __bf16 bf16x8 __attribute__((ext_vector_type(8)));
typedef _Float16 f16x8 __attribute__((ext_vector_type(8)));
typedef float f32x4v __attribute__((ext_vector_type(4)));

#define MB(x) ((size_t)(x) * 262144)   // x MiB in floats

__device__ __forceinline__ float silu_f(float a) {
    return a / (1.0f + __expf(-a));
}
__device__ __forceinline__ u16 f2bf(float f) {
    union { float f; unsigned u; } a; a.f = f;
    unsigned r = a.u + 0x7fffu + ((a.u >> 16) & 1u);
    return (u16)(r >> 16);
}
__device__ __forceinline__ u16 f16bits(f16 h) {
    union { f16 f; u16 u; } a; a.f = h; return a.u;
}

// async global->LDS, 16B per lane (per-lane global addr OK; LDS side is
// wave-uniform base + lane*16)
__device__ __forceinline__ void stage16(const void* g, void* l) {
    __builtin_amdgcn_global_load_lds(
        (const __attribute__((address_space(1))) unsigned int*)g,
        (__attribute__((address_space(3))) unsigned int*)l, 16, 0, 0);
}

// ---------------------------------------------------------------------------
// RMSNorm -> split-f16 hi/lo (attention branch input)
// ---------------------------------------------------------------------------
__global__ __launch_bounds__(256) void rmsnorm_split_k(const float* __restrict__ x,
                                                       const float* __restrict__ w,
                                                       u16* __restrict__ hh,
                                                       u16* __restrict__ hl) {
    int row = blockIdx.x;
    int tid = threadIdx.x;
    const float* xr = x + (size_t)row * Cq;
    float4 v = *(const float4*)(xr + tid * 4);
    float ss = v.x*v.x + v.y*v.y + v.z*v.z + v.w*v.w;
    #pragma unroll
    for (int off = 32; off; off >>= 1) ss += __shfl_xor(ss, off);
    __shared__ float red[4];
    if ((tid & 63) == 0) red[tid >> 6] = ss;
    __syncthreads();
    float tot = red[0] + red[1] + red[2] + red[3];
    float scale = rsqrtf(tot * (1.0f / (float)Cq) + 1e-6f);
    float4 wv = *(const float4*)(w + tid * 4);
    float o[4] = { v.x*wv.x*scale, v.y*wv.y*scale, v.z*wv.z*scale, v.w*wv.w*scale };
    ushort4 oh, ol;
    u16* ph = (u16*)&oh; u16* pl = (u16*)&ol;
    #pragma unroll
    for (int i = 0; i < 4; i++) {
        f16 hi = (f16)o[i]; f16 lo = (f16)(o[i] - (float)hi);
        ph[i] = f16bits(hi); pl[i] = f16bits(lo);
    }
    *(ushort4*)(hh + (size_t)row * Cq + tid * 4) = oh;
    *(ushort4*)(hl + (size_t)row * Cq + tid * 4) = ol;
}

// ---------------------------------------------------------------------------
// RMSNorm -> fp32 + bf16 (FFN branch: fp32 feeds router, bf16 feeds MoE)
// ---------------------------------------------------------------------------
__global__ __launch_bounds__(256) void rmsnorm2_k(const float* __restrict__ x,
                                                  const float* __restrict__ w,
                                                  float* __restrict__ hn,
                                                  u16* __restrict__ hnb) {
    int row = blockIdx.x;
    int tid = threadIdx.x;
    const float* xr = x + (size_t)row * Cq;
    float4 v = *(const float4*)(xr + tid * 4);
    float ss = v.x*v.x + v.y*v.y + v.z*v.z + v.w*v.w;
    #pragma unroll
    for (int off = 32; off; off >>= 1) ss += __shfl_xor(ss, off);
    __shared__ float red[4];
    if ((tid & 63) == 0) red[tid >> 6] = ss;
    __syncthreads();
    float tot = red[0] + red[1] + red[2] + red[3];
    float scale = rsqrtf(tot * (1.0f / (float)Cq) + 1e-6f);
    float4 wv = *(const float4*)(w + tid * 4);
    float4 o = make_float4(v.x*wv.x*scale, v.y*wv.y*scale, v.z*wv.z*scale, v.w*wv.w*scale);
    *(float4*)(hn + (size_t)row * Cq + tid * 4) = o;
    ushort4 ob = make_ushort4(f2bf(o.x), f2bf(o.y), f2bf(o.z), f2bf(o.w));
    *(ushort4*)(hnb + (size_t)row * Cq + tid * 4) = ob;
}

// ---------------------------------------------------------------------------
// Split-f16 MFMA GEMM, pipelined (W-register prefetch + A-LDS double buffer).
// kind 0 (grid 24x32): fused QKV. proj=bx/8: 0=Q (rope+split, scale 1/8),
//   1=K (rope+split), 2=V (fp32 out for vtrans).
// kind 1 (grid 8x32): O-proj, C = acc + aux (residual), fp32 out.
// A pre-split hi/lo u16 planes; W fp32 split hi/lo in-register while staging.
// 3-term MFMA (ah*bh + ah*bl + al*bh) ~ fp32 precision (router-safe).
// ---------------------------------------------------------------------------
__global__ __launch_bounds__(256, 3) void gemm_fused(const u16* __restrict__ Ahg,
                                                     const u16* __restrict__ Alg,
                                                     const float* __restrict__ Wq,
                                                     const float* __restrict__ Wk,
                                                     const float* __restrict__ Wv,
                                                     u16* __restrict__ qh_o,
                                                     u16* __restrict__ ql_o,
                                                     u16* __restrict__ kh_o,
                                                     u16* __restrict__ kl_o,
                                                     float* __restrict__ vf_o,
                                                     const float* __restrict__ cosb,
                                                     const float* __restrict__ sinb,
                                                     const float* __restrict__ aux,
                                                     float* __restrict__ outf,
                                                     int kind) {
    __shared__ u16 AhS[2][128*32], AlS[2][128*32], BhS[128*32], BlS[128*32];
    int tid = threadIdx.x;
    int wave = tid >> 6, lane = tid & 63;
    int wm = wave >> 1, wn = wave & 1;
    int bx = blockIdx.x, by = blockIdx.y;
    int proj, nx;
    const float* W;
    if (kind == 0) {
        proj = bx >> 3; nx = bx & 7;
        W = (proj == 0) ? Wq : ((proj == 1) ? Wk : Wv);
    } else {
        proj = 3; nx = bx; W = Wq;
    }

    int srow = tid >> 2, sch = (tid & 3) * 8;
    const u16* A0 = Ahg + (size_t)(by*128 + srow) * Cq + sch;
    const u16* A1 = A0 + (size_t)64 * Cq;
    const u16* L0 = Alg + (size_t)(by*128 + srow) * Cq + sch;
    const u16* L1 = L0 + (size_t)64 * Cq;
    const float* W0 = W + (size_t)(nx*128 + srow) * Cq + sch;
    const float* W1 = W0 + (size_t)64 * Cq;
    int lo0 = srow*32 + sch, lo1 = lo0 + 2048;

    f32x4v acc[4][4];
    #pragma unroll
    for (int i = 0; i < 4; i++)
        #pragma unroll
        for (int j = 0; j < 4; j++)
            #pragma unroll
            for (int r = 0; r < 4; r++) acc[i][j][r] = 0.0f;

    // prologue: stage A(k=0), prefetch W(k=0)
    float wr0[8], wr1[8];
    stage16(A0, &AhS[0][lo0]);
    stage16(A1, &AhS[0][lo1]);
    stage16(L0, &AlS[0][lo0]);
    stage16(L1, &AlS[0][lo1]);
    *(float4*)&wr0[0] = *(const float4*)(W0);
    *(float4*)&wr0[4] = *(const float4*)(W0 + 4);
    *(float4*)&wr1[0] = *(const float4*)(W1);
    *(float4*)&wr1[4] = *(const float4*)(W1 + 4);

    int fr = lane & 15, fk = (lane >> 4) * 8;
    int cur = 0;
    for (int k0 = 0; k0 < Cq; k0 += 32, cur ^= 1) {
        __syncthreads();   // (a) prev MFMA done with B; A/W loads drained
        {
            f16x8 bh0, bl0, bh1, bl1;
            #pragma unroll
            for (int i = 0; i < 8; i++) {
                f16 h0 = (f16)wr0[i]; bh0[i] = h0; bl0[i] = (f16)(wr0[i] - (float)h0);
                f16 h1 = (f16)wr1[i]; bh1[i] = h1; bl1[i] = (f16)(wr1[i] - (float)h1);
            }
            *(f16x8*)(void*)&BhS[lo0] = bh0;
            *(f16x8*)(void*)&BlS[lo0] = bl0;
            *(f16x8*)(void*)&BhS[lo1] = bh1;
            *(f16x8*)(void*)&BlS[lo1] = bl1;
        }
        __syncthreads();   // (b) B visible, A[cur] complete
        int kn = k0 + 32;
        if (kn < Cq) {     // prefetch next iter under the MFMA phase
            stage16(A0 + kn, &AhS[cur^1][lo0]);
            stage16(A1 + kn, &AhS[cur^1][lo1]);
            stage16(L0 + kn, &AlS[cur^1][lo0]);
            stage16(L1 + kn, &AlS[cur^1][lo1]);
            *(float4*)&wr0[0] = *(const float4*)(W0 + kn);
            *(float4*)&wr0[4] = *(const float4*)(W0 + kn + 4);
            *(float4*)&wr1[0] = *(const float4*)(W1 + kn);
            *(float4*)&wr1[4] = *(const float4*)(W1 + kn + 4);
        }
        f16x8 ah[4], al[4];
        #pragma unroll
        for (int mi = 0; mi < 4; mi++) {
            ah[mi] = *(const f16x8*)(const void*)&AhS[cur][(wm*64 + mi*16 + fr)*32 + fk];
            al[mi] = *(const f16x8*)(const void*)&AlS[cur][(wm*64 + mi*16 + fr)*32 + fk];
        }
        #pragma unroll
        for (int ni = 0; ni < 4; ni++) {
            f16x8 bhf = *(const f16x8*)(const void*)&BhS[(wn*64 + ni*16 + fr)*32 + fk];
            f16x8 blf = *(const f16x8*)(const void*)&BlS[(wn*64 + ni*16 + fr)*32 + fk];
            #pragma unroll
            for (int mi = 0; mi < 4; mi++) {
                acc[mi][ni] = __builtin_amdgcn_mfma_f32_16x16x32_f16(ah[mi], bhf, acc[mi][ni], 0, 0, 0);
                acc[mi][ni] = __builtin_amdgcn_mfma_f32_16x16x32_f16(ah[mi], blf, acc[mi][ni], 0, 0, 0);
                acc[mi][ni] = __builtin_amdgcn_mfma_f32_16x16x32_f16(al[mi], bhf, acc[mi][ni], 0, 0, 0);
            }
        }
    }

    int cr = (lane >> 4) * 4, cc = lane & 15;
    if (proj < 2) {
        // fused RoPE + split-f16 store. Wave's 64 cols = one head; pair
        // (d, d+32) = accumulators (ni, ni+2), in-register.
        u16* dh = (proj == 0) ? qh_o : kh_o;
        u16* dl = (proj == 0) ? ql_o : kl_o;
        float scale = (proj == 0) ? 0.125f : 1.0f;
        int hd = (nx * 2 + wn) * 64;
        #pragma unroll
        for (int mi = 0; mi < 4; mi++)
            #pragma unroll
            for (int r = 0; r < 4; r++) {
                int row = by*128 + wm*64 + mi*16 + cr + r;
                int t = row & (Tq - 1);
                #pragma unroll
                for (int ni = 0; ni < 2; ni++) {
                    int d0 = ni*16 + cc;
                    float a = acc[mi][ni][r];
                    float b = acc[mi][ni+2][r];
                    float c0 = cosb[t*Dq + d0],      s0 = sinb[t*Dq + d0];
                    float c1 = cosb[t*Dq + d0 + 32], s1 = sinb[t*Dq + d0 + 32];
                    float oa = (a * c0 - b * s0) * scale;
                    float ob = (b * c1 + a * s1) * scale;
                    size_t off = (size_t)row * Cq + hd + d0;
                    f16 ha = (f16)oa;
                    f16 hb = (f16)ob;
                    dh[off]      = f16bits(ha);
                    dl[off]      = f16bits((f16)(oa - (float)ha));
                    dh[off + 32] = f16bits(hb);
                    dl[off + 32] = f16bits((f16)(ob - (float)hb));
                }
            }
    } else if (proj == 2) {
        #pragma unroll
        for (int mi = 0; mi < 4; mi++)
            #pragma unroll
            for (int r = 0; r < 4; r++) {
                int row = by*128 + wm*64 + mi*16 + cr + r;
                #pragma unroll
                for (int ni = 0; ni < 4; ni++)
                    vf_o[(size_t)row * Cq + nx*128 + wn*64 + ni*16 + cc] = acc[mi][ni][r];
            }
    } else {
        #pragma unroll
        for (int mi = 0; mi < 4; mi++)
            #pragma unroll
            for (int r = 0; r < 4; r++) {
                int row = by*128 + wm*64 + mi*16 + cr + r;
                #pragma unroll
                for (int ni = 0; ni < 4; ni++) {
                    size_t off = (size_t)row * Cq + nx*128 + wn*64 + ni*16 + cc;
                    outf[off] = acc[mi][ni][r] + aux[off];
                }
            }
    }
}

// ---------------------------------------------------------------------------
// V transpose + split: v fp32 [b][t][h*64+d] -> vth/vtl u16 [bh][d][t]
// ---------------------------------------------------------------------------
__global__ __launch_bounds__(256) void vtrans_k(const float* __restrict__ v,
                                                u16* __restrict__ vth,
                                                u16* __restrict__ vtl) {
    __shared__ u16 Th[64 * 72];
    __shared__ u16 Tl[64 * 72];
    int tc = blockIdx.x;
    int bh = blockIdx.y;
    int b = bh >> 4, h = bh & 15;
    int tid = threadIdx.x;
    int tr = tid >> 2;
    int dc = (tid & 3) * 16;
    size_t gin = ((size_t)(b * Tq + tc * 64 + tr)) * Cq + h * Dq + dc;
    #pragma unroll
    for (int i = 0; i < 16; i += 4) {
        float4 f = *(const float4*)(v + gin + i);
        float fv[4] = {f.x, f.y, f.z, f.w};
        #pragma unroll
        for (int j = 0; j < 4; j++) {
            f16 hi = (f16)fv[j];
            f16 lo = (f16)(fv[j] - (float)hi);
            Th[(dc + i + j) * 72 + tr] = f16bits(hi);
            Tl[(dc + i + j) * 72 + tr] = f16bits(lo);
        }
    }
    __syncthreads();
    int dr = tid >> 2;
    int cc = (tid & 3) * 16;
    size_t gout = ((size_t)(bh * 64 + dr)) * Tq + tc * 64 + cc;
    *(uint4*)(vth + gout)     = *(uint4*)(Th + dr * 72 + cc);
    *(uint4*)(vth + gout + 8) = *(uint4*)(Th + dr * 72 + cc + 8);
    *(uint4*)(vtl + gout)     = *(uint4*)(Tl + dr * 72 + cc);
    *(uint4*)(vtl + gout + 8) = *(uint4*)(Tl + dr * 72 + cc + 8);
}

// ---------------------------------------------------------------------------
// Flash attention, split-fp16 MFMA, triangle-paired, with K/V register
// prefetch: loads for kt+1 issued during kt's MFMA phase (drained at the
// next barrier, latency hidden under compute).
// ---------------------------------------------------------------------------
#define AST 72
__global__ __launch_bounds__(256, 2) void attn_f16(const u16* __restrict__ qh_g,
                                                   const u16* __restrict__ ql_g,
                                                   const u16* __restrict__ kh_g,
                                                   const u16* __restrict__ kl_g,
                                                   const u16* __restrict__ vth_g,
                                                   const u16* __restrict__ vtl_g,
                                                   u16* __restrict__ yh_g,
                                                   u16* __restrict__ yl_g) {
    __shared__ u16 Qh[64*AST], Ql[64*AST];
    __shared__ u16 Kh[64*AST], Kl[64*AST];
    __shared__ u16 Vh[64*AST], Vl[64*AST];
    __shared__ u16 Ph[64*AST], Pl[64*AST];

    int j  = blockIdx.x;           // 0..15
    int bh = blockIdx.y;
    int b = bh >> 4, h = bh & 15;
    int tid = threadIdx.x;
    int wv = tid >> 6, lane = tid & 63;
    int fr = lane & 15, fg = lane >> 4;
    int sr = tid >> 2, sc = (tid & 3) * 16;
    int aoff = (wv * 16 + fr) * AST + fg * 8;

    uint4 rkh0, rkh1, rkl0, rkl1, rvh0, rvh1, rvl0, rvl1;
    auto ldkv = [&](int kt) {
        size_t kg = ((size_t)(b * Tq + kt * 64 + sr)) * Cq + h * Dq + sc;
        size_t vg = ((size_t)(bh * 64 + sr)) * Tq + kt * 64 + sc;
        rkh0 = *(const uint4*)(kh_g + kg);  rkh1 = *(const uint4*)(kh_g + kg + 8);
        rkl0 = *(const uint4*)(kl_g + kg);  rkl1 = *(const uint4*)(kl_g + kg + 8);
        rvh0 = *(const uint4*)(vth_g + vg); rvh1 = *(const uint4*)(vth_g + vg + 8);
        rvl0 = *(const uint4*)(vtl_g + vg); rvl1 = *(const uint4*)(vtl_g + vg + 8);
    };

    #pragma unroll
    for (int pass = 0; pass < 2; pass++) {
        int qt = pass == 0 ? (31 - j) : j;

        __syncthreads();   // prior pass's LDS reads done
        {
            size_t g = ((size_t)(b * Tq + qt * 64 + sr)) * Cq + h * Dq + sc;
            *(uint4*)(Qh + sr*AST + sc)     = *(const uint4*)(qh_g + g);
            *(uint4*)(Qh + sr*AST + sc + 8) = *(const uint4*)(qh_g + g + 8);
            *(uint4*)(Ql + sr*AST + sc)     = *(const uint4*)(ql_g + g);
            *(uint4*)(Ql + sr*AST + sc + 8) = *(const uint4*)(ql_g + g + 8);
        }
        ldkv(0);

        f32x4v acc_o[4];
        float m_i[4], l_i[4];
        #pragma unroll
        for (int i = 0; i < 4; i++) {
            m_i[i] = -1e30f; l_i[i] = 0.0f;
            #pragma unroll
            for (int r = 0; r < 4; r++) acc_o[i][r] = 0.0f;
        }

        for (int kt = 0; kt <= qt; kt++) {
            __syncthreads();   // (a) prev MFMA done reading Ks/Vs
            *(uint4*)(Kh + sr*AST + sc)     = rkh0;
            *(uint4*)(Kh + sr*AST + sc + 8) = rkh1;
            *(uint4*)(Kl + sr*AST + sc)     = rkl0;
            *(uint4*)(Kl + sr*AST + sc + 8) = rkl1;
            *(uint4*)(Vh + sr*AST + sc)     = rvh0;
            *(uint4*)(Vh + sr*AST + sc + 8) = rvh1;
            *(uint4*)(Vl + sr*AST + sc)     = rvl0;
            *(uint4*)(Vl + sr*AST + sc + 8) = rvl1;
            __syncthreads();   // (b) K/V visible
            if (kt < qt) ldkv(kt + 1);   // prefetch under MFMA

            // S = Q K^T (3-term split)
            f16x8 aqh0 = *(const f16x8*)(const void*)(Qh + aoff);
            f16x8 aqh1 = *(const f16x8*)(const void*)(Qh + aoff + 32);
            f16x8 aql0 = *(const f16x8*)(const void*)(Ql + aoff);
            f16x8 aql1 = *(const f16x8*)(const void*)(Ql + aoff + 32);

            f32x4v s[4];
            #pragma unroll
            for (int ni = 0; ni < 4; ni++) {
                int boff = (ni * 16 + fr) * AST + fg * 8;
                f16x8 kh0 = *(const f16x8*)(const void*)(Kh + boff);
                f16x8 kh1 = *(const f16x8*)(const void*)(Kh + boff + 32);
                f16x8 kl0 = *(const f16x8*)(const void*)(Kl + boff);
                f16x8 kl1 = *(const f16x8*)(const void*)(Kl + boff + 32);
                f32x4v t;
                #pragma unroll
                for (int r = 0; r < 4; r++) t[r] = 0.0f;
                t = __builtin_amdgcn_mfma_f32_16x16x32_f16(aqh0, kh0, t, 0, 0, 0);
                t = __builtin_amdgcn_mfma_f32_16x16x32_f16(aqh1, kh1, t, 0, 0, 0);
                t = __builtin_amdgcn_mfma_f32_16x16x32_f16(aqh0, kl0, t, 0, 0, 0);
                t = __builtin_amdgcn_mfma_f32_16x16x32_f16(aqh1, kl1, t, 0, 0, 0);
                t = __builtin_amdgcn_mfma_f32_16x16x32_f16(aql0, kh0, t, 0, 0, 0);
                t = __builtin_amdgcn_mfma_f32_16x16x32_f16(aql1, kh1, t, 0, 0, 0);
                s[ni] = t;
            }

            if (kt == qt) {
                #pragma unroll
                for (int ni = 0; ni < 4; ni++) {
                    int col = ni * 16 + fr;
                    #pragma unroll
                    for (int r = 0; r < 4; r++) {
                        int row = wv * 16 + fg * 4 + r;
                        if (col > row) s[ni][r] = -1e30f;
                    }
                }
            }

            // online softmax
            float p[4][4];
            #pragma unroll
            for (int r = 0; r < 4; r++) {
                float mx = fmaxf(fmaxf(s[0][r], s[1][r]), fmaxf(s[2][r], s[3][r]));
                #pragma unroll
                for (int off = 1; off < 16; off <<= 1)
                    mx = fmaxf(mx, __shfl_xor(mx, off, 16));
                float mn = fmaxf(m_i[r], mx);
                float rs = 0.0f;
                #pragma unroll
                for (int ni = 0; ni < 4; ni++) {
                    p[ni][r] = __expf(s[ni][r] - mn);
                    rs += p[ni][r];
                }
                #pragma unroll
                for (int off = 1; off < 16; off <<= 1)
                    rs += __shfl_xor(rs, off, 16);
                float alpha = __expf(m_i[r] - mn);
                l_i[r] = l_i[r] * alpha + rs;
                m_i[r] = mn;
                #pragma unroll
                for (int ni = 0; ni < 4; ni++) acc_o[ni][r] *= alpha;
            }

            // write P (split); rows are wave-private, no barrier needed
            #pragma unroll
            for (int ni = 0; ni < 4; ni++) {
                #pragma unroll
                for (int r = 0; r < 4; r++) {
                    int off = (wv * 16 + fg * 4 + r) * AST + ni * 16 + fr;
                    f16 ph = (f16)p[ni][r];
                    f16 pl = (f16)(p[ni][r] - (float)ph);
                    Ph[off] = f16bits(ph);
                    Pl[off] = f16bits(pl);
                }
            }

            // O += P V (3-term split)
            f16x8 aph0 = *(const f16x8*)(const void*)(Ph + aoff);
            f16x8 aph1 = *(const f16x8*)(const void*)(Ph + aoff + 32);
            f16x8 apl0 = *(const f16x8*)(const void*)(Pl + aoff);
            f16x8 apl1 = *(const f16x8*)(const void*)(Pl + aoff + 32);
            #pragma unroll
            for (int ni = 0; ni < 4; ni++) {
                int boff = (ni * 16 + fr) * AST + fg * 8;
                f16x8 vh0 = *(const f16x8*)(const void*)(Vh + boff);
                f16x8 vh1 = *(const f16x8*)(const void*)(Vh + boff + 32);
                f16x8 vl0 = *(const f16x8*)(const void*)(Vl + boff);
                f16x8 vl1 = *(const f16x8*)(const void*)(Vl + boff + 32);
                f32x4v t = acc_o[ni];
                t = __builtin_amdgcn_mfma_f32_16x16x32_f16(aph0, vh0, t, 0, 0, 0);
                t = __builtin_amdgcn_mfma_f32_16x16x32_f16(aph1, vh1, t, 0, 0, 0);
                t = __builtin_amdgcn_mfma_f32_16x16x32_f16(aph0, vl0, t, 0, 0, 0);
                t = __builtin_amdgcn_mfma_f32_16x16x32_f16(aph1, vl1, t, 0, 0, 0);
                t = __builtin_amdgcn_mfma_f32_16x16x32_f16(apl0, vh0, t, 0, 0, 0);
                t = __builtin_amdgcn_mfma_f32_16x16x32_f16(apl1, vh1, t, 0, 0, 0);
                acc_o[ni] = t;
            }
        }

        // epilogue: split y write
        #pragma unroll
        for (int r = 0; r < 4; r++) {
            float inv = 1.0f / l_i[r];
            int row = qt * 64 + wv * 16 + fg * 4 + r;
            size_t base = ((size_t)(b * Tq + row)) * Cq + h * Dq + fr;
            #pragma unroll
            for (int ni = 0; ni < 4; ni++) {
                float yv = acc_o[ni][r] * inv;
                f16 hi = (f16)yv;
                f16 lo = (f16)(yv - (float)hi);
                yh_g[base + ni * 16] = f16bits(hi);
                yl_g[base + ni * 16] = f16bits(lo);
            }
        }
    }
}

// ---------------------------------------------------------------------------
// Zero the expert counters (ws is poisoned before every call)
// ---------------------------------------------------------------------------
__global__ void zero_k(int* cnt) {
    if (threadIdx.x < Eq) cnt[threadIdx.x] = 0;
}

// ---------------------------------------------------------------------------
// Router: fp32 logits, top-2; emit per-expert (token, gate) lists via atomics.
// ---------------------------------------------------------------------------
__global__ __launch_bounds__(64) void router_k(const float* __restrict__ hn,
                                               const float* __restrict__ rw,
                                               int* __restrict__ cnt,
                                               int* __restrict__ idxl,
                                               float* __restrict__ gvl) {
    int tkn = blockIdx.x;
    int lane = threadIdx.x;
    float acc[Eq] = {};
    for (int it = 0; it < Cq / 64; it++) {
        float hv = hn[(size_t)tkn * Cq + it * 64 + lane];
        #pragma unroll
        for (int e = 0; e < Eq; e++)
            acc[e] = fmaf(hv, rw[e * Cq + it * 64 + lane], acc[e]);
    }
    #pragma unroll
    for (int e = 0; e < Eq; e++) {
        #pragma unroll
        for (int off = 32; off; off >>= 1) acc[e] += __shfl_xor(acc[e], off);
    }
    int i0 = 0;
    #pragma unroll
    for (int e = 1; e < Eq; e++) if (acc[e] > acc[i0]) i0 = e;
    int i1 = (i0 == 0) ? 1 : 0;
    #pragma unroll
    for (int e = 0; e < Eq; e++)
        if (e != i0 && acc[e] > acc[i1]) i1 = e;
    float p1 = __expf(acc[i1] - acc[i0]);
    float g0 = 1.0f / (1.0f + p1);
    float g1 = p1 / (1.0f + p1);
    if (lane == 0) {
        int p0 = atomicAdd(&cnt[i0], 1);
        idxl[i0 * NTOK + p0] = tkn;
        gvl[i0 * NTOK + p0] = g0;
        int p1i = atomicAdd(&cnt[i1], 1);
        idxl[i1 * NTOK + p1i] = tkn;
        gvl[i1 * NTOK + p1i] = g1;
    }
}

// ---------------------------------------------------------------------------
// Setup: 128-padded segment offsets + tile->expert table (<= 72 tiles).
// ---------------------------------------------------------------------------
__global__ void setup_k(const int* __restrict__ cnt, int* __restrict__ seg,
                        int* __restrict__ texp, int* __restrict__ ttot) {
    if (threadIdx.x == 0) {
        int base = 0;
        for (int e = 0; e < Eq; e++) {
            seg[e] = base * 128;
            int t = (cnt[e] + 127) >> 7;
            for (int i = 0; i < t; i++) texp[base + i] = e;
            base += t;
        }
        *ttot = base;
    }
}

// ---------------------------------------------------------------------------
// MoE up-proj, pipelined: gbuf = bf16(silu(A@w1^T) * (A@w3^T)).
// A rows gathered in-staging (per-lane global addrs), double-buffered LDS;
// w1/w3 fp32 prefetched into registers during the MFMA phase.
// ---------------------------------------------------------------------------
__global__ __launch_bounds__(256, 2) void moe_w13(const u16* __restrict__ hnb,
                                                  const float* __restrict__ w1,
                                                  const float* __restrict__ w3,
                                                  u16* __restrict__ gbuf,
                                                  const int* __restrict__ cnt,
                                                  const int* __restrict__ seg,
                                                  const int* __restrict__ texp,
                                                  const int* __restrict__ ttot,
                                                  const int* __restrict__ idxl) {
    int by = blockIdx.y;
    if (by >= *ttot) return;
    int e = texp[by];
    const float* w1e = w1 + (size_t)e * HDq * Cq;
    const float* w3e = w3 + (size_t)e * HDq * Cq;
    int cnte = cnt[e], sege = seg[e];
    const int* idxe = idxl + e * NTOK;

    __shared__ u16 As[2][128*32], B1S[128*32], B3S[128*32];
    int tid = threadIdx.x;
    int wave = tid >> 6, lane = tid & 63;
    int wm = wave >> 1, wn = wave & 1;
    int bx = blockIdx.x;
    int srow = tid >> 2, sch = (tid & 3) * 8;

    int r0 = by*128 + srow, r1 = r0 + 64;
    int li0 = r0 - sege, li1 = r1 - sege;
    int tok0 = idxe[li0 < cnte ? li0 : 0];
    int tok1 = idxe[li1 < cnte ? li1 : 0];
    const u16* A0 = hnb + (size_t)tok0 * Cq + sch;
    const u16* A1 = hnb + (size_t)tok1 * Cq + sch;
    const float* W10 = w1e + (size_t)(bx*128 + srow) * Cq + sch;
    const float* W11 = W10 + (size_t)64 * Cq;
    const float* W30 = w3e + (size_t)(bx*128 + srow) * Cq + sch;
    const float* W31 = W30 + (size_t)64 * Cq;
    int lo0 = srow*32 + sch, lo1 = lo0 + 2048;

    f32x4v acc1[4][4], acc3[4][4];
    #pragma unroll
    for (int i = 0; i < 4; i++)
        #pragma unroll
        for (int j = 0; j < 4; j++)
            #pragma unroll
            for (int r = 0; r < 4; r++) { acc1[i][j][r] = 0.0f; acc3[i][j][r] = 0.0f; }

    float x1a[8], x1b[8], x3a[8], x3b[8];
    stage16(A0, &As[0][lo0]);
    stage16(A1, &As[0][lo1]);
    *(float4*)&x1a[0] = *(const float4*)(W10);
    *(float4*)&x1a[4] = *(const float4*)(W10 + 4);
    *(float4*)&x1b[0] = *(const float4*)(W11);
    *(float4*)&x1b[4] = *(const float4*)(W11 + 4);
    *(float4*)&x3a[0] = *(const float4*)(W30);
    *(float4*)&x3a[4] = *(const float4*)(W30 + 4);
    *(float4*)&x3b[0] = *(const float4*)(W31);
    *(float4*)&x3b[4] = *(const float4*)(W31 + 4);

    int fr = lane & 15, fk = (lane >> 4) * 8;
    int cur = 0;
    for (int k0 = 0; k0 < Cq; k0 += 32, cur ^= 1) {
        __syncthreads();   // (a)
        {
            u16 t0[8], t1[8], t2[8], t3[8];
            #pragma unroll
            for (int i = 0; i < 8; i++) {
                t0[i] = f2bf(x1a[i]); t1[i] = f2bf(x1b[i]);
                t2[i] = f2bf(x3a[i]); t3[i] = f2bf(x3b[i]);
            }
            *(uint4*)&B1S[lo0] = *(uint4*)t0;
            *(uint4*)&B1S[lo1] = *(uint4*)t1;
            *(uint4*)&B3S[lo0] = *(uint4*)t2;
            *(uint4*)&B3S[lo1] = *(uint4*)t3;
        }
        __syncthreads();   // (b)
        int kn = k0 + 32;
        if (kn < Cq) {
            stage16(A0 + kn, &As[cur^1][lo0]);
            stage16(A1 + kn, &As[cur^1][lo1]);
            *(float4*)&x1a[0] = *(const float4*)(W10 + kn);
            *(float4*)&x1a[4] = *(const float4*)(W10 + kn + 4);
            *(float4*)&x1b[0] = *(const float4*)(W11 + kn);
            *(float4*)&x1b[4] = *(const float4*)(W11 + kn + 4);
            *(float4*)&x3a[0] = *(const float4*)(W30 + kn);
            *(float4*)&x3a[4] = *(const float4*)(W30 + kn + 4);
            *(float4*)&x3b[0] = *(const float4*)(W31 + kn);
            *(float4*)&x3b[4] = *(const float4*)(W31 + kn + 4);
        }
        bf16x8 af[4];
        #pragma unroll
        for (int mi = 0; mi < 4; mi++)
            af[mi] = *(const bf16x8*)&As[cur][(wm*64 + mi*16 + fr) * 32 + fk];
        #pragma unroll
        for (int ni = 0; ni < 4; ni++) {
            bf16x8 b1f = *(const bf16x8*)&B1S[(wn*64 + ni*16 + fr) * 32 + fk];
            bf16x8 b3f = *(const bf16x8*)&B3S[(wn*64 + ni*16 + fr) * 32 + fk];
            #pragma unroll
            for (int mi = 0; mi < 4; mi++) {
                acc1[mi][ni] = __builtin_amdgcn_mfma_f32_16x16x32_bf16(af[mi], b1f, acc1[mi][ni], 0, 0, 0);
                acc3[mi][ni] = __builtin_amdgcn_mfma_f32_16x16x32_bf16(af[mi], b3f, acc3[mi][ni], 0, 0, 0);
            }
        }
    }

    int cr = (lane >> 4) * 4, cc = lane & 15;
    #pragma unroll
    for (int mi = 0; mi < 4; mi++)
        #pragma unroll
        for (int ni = 0; ni < 4; ni++)
            #pragma unroll
            for (int r = 0; r < 4; r++) {
                int row = by*128 + wm*64 + mi*16 + cr + r;
                int col = bx*128 + wn*64 + ni*16 + cc;
                gbuf[(size_t)row * HDq + col] = f2bf(silu_f(acc1[mi][ni][r]) * acc3[mi][ni][r]);
            }
}

// ---------------------------------------------------------------------------
// MoE down-proj, pipelined: out[token] += gate * (gbuf @ w2^T), atomics.
// ---------------------------------------------------------------------------
__global__ __launch_bounds__(256, 3) void moe_w2(const u16* __restrict__ gbuf,
                                                 const float* __restrict__ w2,
                                                 float* __restrict__ out,
                                                 const int* __restrict__ cnt,
                                                 const int* __restrict__ seg,
                                                 const int* __restrict__ texp,
                                                 const int* __restrict__ ttot,
                                                 const int* __restrict__ idxl,
                                                 const float* __restrict__ gvl) {
    int by = blockIdx.y;
    if (by >= *ttot) return;
    int e = texp[by];
    const float* w2e = w2 + (size_t)e * Cq * HDq;
    int cnte = cnt[e], sege = seg[e];
    const int* idxe = idxl + e * NTOK;
    const float* gve = gvl + e * NTOK;

    __shared__ u16 As[2][128*32], Bs[128*32];
    int tid = threadIdx.x;
    int wave = tid >> 6, lane = tid & 63;
    int wm = wave >> 1, wn = wave & 1;
    int bx = blockIdx.x;
    int srow = tid >> 2, sch = (tid & 3) * 8;

    const u16* A0 = gbuf + (size_t)(by*128 + srow) * HDq + sch;
    const u16* A1 = A0 + (size_t)64 * HDq;
    const float* W0 = w2e + (size_t)(bx*128 + srow) * HDq + sch;
    const float* W1 = W0 + (size_t)64 * HDq;
    int lo0 = srow*32 + sch, lo1 = lo0 + 2048;

    f32x4v acc[4][4];
    #pragma unroll
    for (int i = 0; i < 4; i++)
        #pragma unroll
        for (int j = 0; j < 4; j++)
            #pragma unroll
            for (int r = 0; r < 4; r++) acc[i][j][r] = 0.0f;

    float xa[8], xb[8];
    stage16(A0, &As[0][lo0]);
    stage16(A1, &As[0][lo1]);
    *(float4*)&xa[0] = *(const float4*)(W0);
    *(float4*)&xa[4] = *(const float4*)(W0 + 4);
    *(float4*)&xb[0] = *(const float4*)(W1);
    *(float4*)&xb[4] = *(const float4*)(W1 + 4);

    int fr = lane & 15, fk = (lane >> 4) * 8;
    int cur = 0;
    for (int k0 = 0; k0 < HDq; k0 += 32, cur ^= 1) {
        __syncthreads();
        {
            u16 ta[8], tb[8];
            #pragma unroll
            for (int i = 0; i < 8; i++) { ta[i] = f2bf(xa[i]); tb[i] = f2bf(xb[i]); }
            *(uint4*)&Bs[lo0] = *(uint4*)ta;
            *(uint4*)&Bs[lo1] = *(uint4*)tb;
        }
        __syncthreads();
        int kn = k0 + 32;
        if (kn < HDq) {
            stage16(A0 + kn, &As[cur^1][lo0]);
            stage16(A1 + kn, &As[cur^1][lo1]);
            *(float4*)&xa[0] = *(const float4*)(W0 + kn);
            *(float4*)&xa[4] = *(const float4*)(W0 + kn + 4);
            *(float4*)&xb[0] = *(const float4*)(W1 + kn);
            *(float4*)&xb[4] = *(const float4*)(W1 + kn + 4);
        }
        bf16x8 af[4];
        #pragma unroll
        for (int mi = 0; mi < 4; mi++)
            af[mi] = *(const bf16x8*)&As[cur][(wm*64 + mi*16 + fr) * 32 + fk];
        #pragma unroll
        for (int ni = 0; ni < 4; ni++) {
            bf16x8 bf_ = *(const bf16x8*)&Bs[(wn*64 + ni*16 + fr) * 32 + fk];
            #pragma unroll
            for (int mi = 0; mi < 4; mi++)
                acc[mi][ni] = __builtin_amdgcn_mfma_f32_16x16x32_bf16(af[mi], bf_, acc[mi][ni], 0, 0, 0);
        }
    }

    int cr = (lane >> 4) * 4, cc = lane & 15;
    #pragma unroll
    for (int mi = 0; mi < 4; mi++)
        #pragma unroll
        for (int r = 0; r < 4; r++) {
            int row = by*128 + wm*64 + mi*16 + cr + r;
            int local = row - sege;
            if (local < cnte) {
                int token = idxe[local];
                float g = gve[local];
                #pragma unroll
                for (int ni = 0; ni < 4; ni++) {
                    int col = bx*128 + wn*64 + ni*16 + cc;
                    atomicAdd(&out[(size_t)token * Cq + col], g * acc[mi][ni][r]);
                }
            }
        }
}

// ---------------------------------------------------------------------------
// Launch
// ---------------------------------------------------------------------------
extern "C" void kernel_launch(void* const* d_in, const int* in_sizes, int n_in,
                              void* d_out, int out_size, void* d_ws, size_t ws_size,
                              hipStream_t stream) {
    (void)in_sizes; (void)n_in; (void)out_size; (void)ws_size;

    const float* x     = (const float*)d_in[0];
    const float* ropec = (const float*)d_in[1];
    const float* ropes = (const float*)d_in[2];
    const float* anw   = (const float*)d_in[3];
    const float* q_w   = (const float*)d_in[4];
    const float* k_w   = (const float*)d_in[5];
    const float* v_w   = (const float*)d_in[6];
    const float* o_w   = (const float*)d_in[7];
    const float* fnw   = (const float*)d_in[8];
    const float* rtw   = (const float*)d_in[9];
    const float* w1    = (const float*)d_in[10];
    const float* w2    = (const float*)d_in[11];
    const float* w3    = (const float*)d_in[12];
    float* out = (float*)d_out;

    // workspace map (MiB offsets; peak 64 MiB, same proven envelope):
    //  P1 (QKV): hh@0-8 hl@8-16 | vf fp32@16-32 | qh@32-40 ql@40-48 kh@48-56 kl@56-64
    //  P2 (attn): vth@0-8 vtl@8-16 (vf dead) | yh@16-24 yl@24-32 (after attn)
    //  P3 (MoE): gbuf@0-28 (yh/yl dead after O-proj) | hn@16?? -> hn@32-48 hnb@48-56 meta@56-57
    float* ws = (float*)d_ws;
    u16* hh = (u16*)(ws + MB(0));
    u16* hl = (u16*)(ws + MB(8));
    float* vf = ws + MB(16);
    u16* qh = (u16*)(ws + MB(32));
    u16* ql = (u16*)(ws + MB(40));
    u16* kh = (u16*)(ws + MB(48));
    u16* kl = (u16*)(ws + MB(56));
    u16* vth = (u16*)(ws + MB(0));
    u16* vtl = (u16*)(ws + MB(8));
    u16* yh  = (u16*)(ws + MB(16));
    u16* yl  = (u16*)(ws + MB(24));
    u16* gbuf = (u16*)(ws + MB(0));           // 9216x1536 bf16 = 27 MiB
    float* hn = ws + MB(32);                  // 16 MiB fp32
    u16* hnb  = (u16*)(ws + MB(48));          // 8 MiB
    int* cntp = (int*)(ws + MB(56));
    int* segp = cntp + 8;
    int* texp = cntp + 16;    // 72 entries
    int* ttot = cntp + 96;
    int* idxl = cntp + 256;                   // 8*4096 ints
    float* gvl = (float*)(cntp + 256 + Eq*NTOK);

    const int M = NTOK;

    // 1. attn rmsnorm -> split hi/lo
    hipLaunchKernelGGL(rmsnorm_split_k, dim3(M), dim3(256), 0, stream, x, anw, hh, hl);

    // 2. fused Q,K,V projection + RoPE + split epilogues (V -> fp32 vf)
    hipLaunchKernelGGL(gemm_fused, dim3(24, M/128), dim3(256), 0, stream,
                       hh, hl, q_w, k_w, v_w, qh, ql, kh, kl, vf,
                       ropec, ropes, (const float*)nullptr, (float*)nullptr, 0);

    // 3. V transpose+split -> vth/vtl (hh/hl region, dead)
    hipLaunchKernelGGL(vtrans_k, dim3(32, 32), dim3(256), 0, stream, vf, vth, vtl);

    // 4. flash attention (triangle-paired, K/V prefetch) -> yh/yl
    hipLaunchKernelGGL(attn_f16, dim3(16, Bq*Hq), dim3(256), 0, stream,
                       qh, ql, kh, kl, vth, vtl, yh, yl);

    // 5. O projection + residual -> out
    hipLaunchKernelGGL(gemm_fused, dim3(8, M/128), dim3(256), 0, stream,
                       yh, yl, o_w, (const float*)nullptr, (const float*)nullptr,
                       (u16*)nullptr, (u16*)nullptr, (u16*)nullptr, (u16*)nullptr,
                       (float*)nullptr, ropec, ropes, x, out, 1);

    // 6. ffn rmsnorm -> hn fp32 + hnb bf16
    hipLaunchKernelGGL(rmsnorm2_k, dim3(M), dim3(256), 0, stream, out, fnw, hn, hnb);

    // 7. router (fp32) -> per-expert lists; then tile table
    hipLaunchKernelGGL(zero_k, dim3(1), dim3(64), 0, stream, cntp);
    hipLaunchKernelGGL(router_k, dim3(M), dim3(64), 0, stream, hn, rtw, cntp, idxl, gvl);
    hipLaunchKernelGGL(setup_k, dim3(1), dim3(64), 0, stream, cntp, segp, texp, ttot);

    // 8. MoE over gathered tokens
    hipLaunchKernelGGL(moe_w13, dim3(HDq/128, 72), dim3(256), 0, stream,
                       hnb, w1, w3, gbuf, cntp, segp, texp, ttot, idxl);
    hipLaunchKernelGGL(moe_w2, dim3(Cq/128, 72), dim3(256), 0, stream,
                       gbuf, w2, out, cntp, segp, texp, ttot, idxl, gvl);
}